// Round 1
// 475.589 us; speedup vs baseline: 1.0954x; 1.0954x over previous
//
#include <hip/hip_runtime.h>

#define M_ 8
#define B_ 64
#define S_ 128
#define D_ 512
#define H_ 8
#define FF_ 1024
#define HD_ 64

typedef __bf16 bf16x8 __attribute__((ext_vector_type(8)));
typedef float f32x4 __attribute__((ext_vector_type(4)));

__device__ __forceinline__ float bf2f(ushort u) {
    union { unsigned int i; float f; } x; x.i = ((unsigned int)u) << 16; return x.f;
}
__device__ __forceinline__ ushort f2bf(float f) {
    union { unsigned int i; float f; } x; x.f = f;
    unsigned int i = x.i;
    return (ushort)((i + 0x7FFFu + ((i >> 16) & 1u)) >> 16);
}
__device__ __forceinline__ void pack8(const float4 a, const float4 b, uint4* dst) {
    union { ushort u[8]; uint4 v; } t;
    t.u[0] = f2bf(a.x); t.u[1] = f2bf(a.y); t.u[2] = f2bf(a.z); t.u[3] = f2bf(a.w);
    t.u[4] = f2bf(b.x); t.u[5] = f2bf(b.y); t.u[6] = f2bf(b.z); t.u[7] = f2bf(b.w);
    *dst = t.v;
}

// Barrier that does NOT drain vmcnt: LDS-visibility only. Prefetched global
// loads stay in flight across it (the whole point of the pipeline).
__device__ __forceinline__ void lds_sync() {
    __builtin_amdgcn_sched_barrier(0);
    asm volatile("s_waitcnt lgkmcnt(0)" ::: "memory");
    __builtin_amdgcn_s_barrier();
    __builtin_amdgcn_sched_barrier(0);
}

// ---------------------------------------------------------------------------
// 64x64-output-tile GEMM over K. Double-buffered LDS + depth-1 register
// prefetch; ONE lgkm-only barrier per K-step (vmcnt stays counted).
// Xs/Ws must each hold 2*64*40 shorts.
// ---------------------------------------------------------------------------
__device__ __forceinline__ void gemm64_fw(const float* __restrict__ X, int ldx,
                                          const float* __restrict__ Wc, int ldw,
                                          int K, short* Xs, short* Ws, f32x4* acc)
{
    const int tid = threadIdx.x, lane = tid & 63, wv = tid >> 6;
    const int c16 = lane & 15, koffs = (lane >> 4) * 8;
    const int xr = tid >> 2, xk = (tid & 3) * 8;
    const int wn = tid & 63, wk = (tid >> 6) * 8;

    float4 xa, xb; float wf[8];
    {
        const float* xp = X + xr * ldx + xk;
        xa = *(const float4*)xp; xb = *(const float4*)(xp + 4);
        const float* wp = Wc + wk * ldw + wn;
        #pragma unroll
        for (int j = 0; j < 8; ++j) wf[j] = wp[j * ldw];
    }
    #pragma unroll 1
    for (int k0 = 0; k0 < K; k0 += 32) {
        short* xs = Xs + ((k0 >> 5) & 1) * 2560;
        short* ws = Ws + ((k0 >> 5) & 1) * 2560;
        const int kn = (k0 + 32 < K) ? k0 + 32 : 0;   // last-iter prefetch is a dummy
        const float* xp = X + xr * ldx + kn + xk;
        float4 nxa = *(const float4*)xp, nxb = *(const float4*)(xp + 4);
        float nwf[8];
        const float* wp = Wc + (kn + wk) * ldw + wn;
        #pragma unroll
        for (int j = 0; j < 8; ++j) nwf[j] = wp[j * ldw];
        __builtin_amdgcn_sched_barrier(0);            // keep prefetch issued first

        pack8(xa, xb, (uint4*)&xs[xr * 40 + xk]);
        union { ushort u[8]; uint4 v; } tw;
        #pragma unroll
        for (int j = 0; j < 8; ++j) tw.u[j] = f2bf(wf[j]);
        *(uint4*)&ws[wn * 40 + wk] = tw.v;
        lds_sync();
        bf16x8 a = *(const bf16x8*)&xs[(16 * wv + c16) * 40 + koffs];
        #pragma unroll
        for (int t = 0; t < 4; ++t) {
            bf16x8 bfr = *(const bf16x8*)&ws[(16 * t + c16) * 40 + koffs];
            acc[t] = __builtin_amdgcn_mfma_f32_16x16x32_bf16(a, bfr, acc[t], 0, 0, 0);
        }
        xa = nxa; xb = nxb;
        #pragma unroll
        for (int j = 0; j < 8; ++j) wf[j] = nwf[j];
    }
}

// Same but X is a bf16 (ushort) workspace tensor.
__device__ __forceinline__ void gemm64_bw(const ushort* __restrict__ X, int ldx,
                                          const float* __restrict__ Wc, int ldw,
                                          int K, short* Xs, short* Ws, f32x4* acc)
{
    const int tid = threadIdx.x, lane = tid & 63, wv = tid >> 6;
    const int c16 = lane & 15, koffs = (lane >> 4) * 8;
    const int xr = tid >> 2, xk = (tid & 3) * 8;
    const int wn = tid & 63, wk = (tid >> 6) * 8;

    uint4 xv; float wf[8];
    {
        xv = *(const uint4*)&X[xr * ldx + xk];
        const float* wp = Wc + wk * ldw + wn;
        #pragma unroll
        for (int j = 0; j < 8; ++j) wf[j] = wp[j * ldw];
    }
    #pragma unroll 1
    for (int k0 = 0; k0 < K; k0 += 32) {
        short* xs = Xs + ((k0 >> 5) & 1) * 2560;
        short* ws = Ws + ((k0 >> 5) & 1) * 2560;
        const int kn = (k0 + 32 < K) ? k0 + 32 : 0;
        uint4 nxv = *(const uint4*)&X[xr * ldx + kn + xk];
        float nwf[8];
        const float* wp = Wc + (kn + wk) * ldw + wn;
        #pragma unroll
        for (int j = 0; j < 8; ++j) nwf[j] = wp[j * ldw];
        __builtin_amdgcn_sched_barrier(0);

        *(uint4*)&xs[xr * 40 + xk] = xv;
        union { ushort u[8]; uint4 v; } tw;
        #pragma unroll
        for (int j = 0; j < 8; ++j) tw.u[j] = f2bf(wf[j]);
        *(uint4*)&ws[wn * 40 + wk] = tw.v;
        lds_sync();
        bf16x8 a = *(const bf16x8*)&xs[(16 * wv + c16) * 40 + koffs];
        #pragma unroll
        for (int t = 0; t < 4; ++t) {
            bf16x8 bfr = *(const bf16x8*)&ws[(16 * t + c16) * 40 + koffs];
            acc[t] = __builtin_amdgcn_mfma_f32_16x16x32_bf16(a, bfr, acc[t], 0, 0, 0);
        }
        xv = nxv;
        #pragma unroll
        for (int j = 0; j < 8; ++j) wf[j] = nwf[j];
    }
}

// ---------------------------------------------------------------------------
// Kernel 1: q = prev_query @ Wq + bq   [M,B,D] (bf16 to ws). grid (D/64, M)
// ---------------------------------------------------------------------------
__global__ __launch_bounds__(256) void k_qproj(const float* __restrict__ prev_query,
                                               const float* __restrict__ Wq,
                                               const float* __restrict__ bq,
                                               ushort* __restrict__ q_ws)
{
    __shared__ __align__(16) short Xs[2 * 64 * 40];
    __shared__ __align__(16) short Ws[2 * 64 * 40];
    const int cb = blockIdx.x, m = blockIdx.y;
    f32x4 acc[4] = {};
    gemm64_fw(prev_query + m * B_ * D_, D_, Wq + m * D_ * D_ + cb * 64, D_, D_, Xs, Ws, acc);
    const int lane = threadIdx.x & 63, wv = threadIdx.x >> 6;
    #pragma unroll
    for (int t = 0; t < 4; ++t)
        #pragma unroll
        for (int r = 0; r < 4; ++r) {
            int row = 16 * wv + (lane >> 4) * 4 + r;
            int col = cb * 64 + 16 * t + (lane & 15);
            q_ws[(m * B_ + row) * D_ + col] = f2bf(acc[t][r] + bq[m * D_ + col]);
        }
}

// ---------------------------------------------------------------------------
// Kernel 2: q~[mh, b, k] = sum_j qh[m,b,h*64+j] * Wk[m][k, h*64+j]
// (project query through Wk^T; bk drops out of softmax). grid (8 kb, H, M).
// ---------------------------------------------------------------------------
__global__ __launch_bounds__(256) void k_qtilde(const ushort* __restrict__ q_ws,
                                                const float* __restrict__ Wk,
                                                ushort* __restrict__ qt_ws)
{
    const int kb = blockIdx.x, h = blockIdx.y, m = blockIdx.z;
    __shared__ __align__(16) short As[64 * 72];
    __shared__ __align__(16) short Ws[64 * 72];
    const int tid = threadIdx.x, lane = tid & 63, wv = tid >> 6;
    {   // stage A = qh [b=64][j=64]
        int r = lane, jj = wv * 16;
        const ushort* src = q_ws + (m * B_ + r) * D_ + h * HD_ + jj;
        *(uint4*)&As[r * 72 + jj]     = *(const uint4*)src;
        *(uint4*)&As[r * 72 + jj + 8] = *(const uint4*)(src + 8);
    }
    {   // stage B[j][n=k] = Wk[m][kb*64+n, h*64+j]
        int n = lane, jj = wv * 16;
        const float* src = Wk + m * D_ * D_ + (kb * 64 + n) * D_ + h * HD_ + jj;
        pack8(*(const float4*)src, *(const float4*)(src + 4), (uint4*)&Ws[n * 72 + jj]);
        pack8(*(const float4*)(src + 8), *(const float4*)(src + 12), (uint4*)&Ws[n * 72 + jj + 8]);
    }
    __syncthreads();
    const int c16 = lane & 15, koffs = (lane >> 4) * 8;
    f32x4 acc[4] = {};
    #pragma unroll
    for (int j0 = 0; j0 < 64; j0 += 32) {
        bf16x8 a = *(const bf16x8*)&As[(16 * wv + c16) * 72 + j0 + koffs];
        #pragma unroll
        for (int t = 0; t < 4; ++t) {
            bf16x8 bfr = *(const bf16x8*)&Ws[(16 * t + c16) * 72 + j0 + koffs];
            acc[t] = __builtin_amdgcn_mfma_f32_16x16x32_bf16(a, bfr, acc[t], 0, 0, 0);
        }
    }
    const int mh = m * H_ + h;
    #pragma unroll
    for (int t = 0; t < 4; ++t)
        #pragma unroll
        for (int r = 0; r < 4; ++r) {
            int row = 16 * wv + (lane >> 4) * 4 + r;     // b
            int col = kb * 64 + 16 * t + (lane & 15);    // k
            qt_ws[(mh * B_ + row) * D_ + col] = f2bf(acc[t][r]);
        }
}

// ---------------------------------------------------------------------------
// Kernel 3: per (b, half): scores -> softmax -> v~. grid (2, B).
// Phase 1 now double-buffered + prefetched with lgkm-only barriers.
// ---------------------------------------------------------------------------
__global__ __launch_bounds__(256) void k_attn2(const float* __restrict__ key_in,
                                               const float* __restrict__ value_in,
                                               const ushort* __restrict__ qt_ws,
                                               ushort* __restrict__ vt_ws)
{
    const int half = blockIdx.x, b = blockIdx.y;
    const int mh0 = half * 32;
    __shared__ __align__(16) short As[2 * 32 * 40];
    __shared__ __align__(16) short Ks[2 * 128 * 40];
    __shared__ __align__(16) short Vs[512 * 40];
    __shared__ float scs[32 * 132];
    __shared__ __align__(16) short wbuf[32 * 136];
    const int tid = threadIdx.x, lane = tid & 63, wv = tid >> 6;
    const int c16 = lane & 15, koffs = (lane >> 4) * 8;
    const int wr = wv >> 1, wc = wv & 1;
    const int BD = B_ * D_;

    // ---- phase 1: scores GEMM, out [32 mh x 128 s], K = 512 ----
    f32x4 acc[4] = {};
    const int ar = tid >> 3, ak = (tid & 7) * 4;
    const int ksr = tid >> 1, kkk = (tid & 1) * 16;
    uint2 av; float4 kv0, kv1, kv2, kv3;
    {
        av = *(const uint2*)&qt_ws[((mh0 + ar) * B_ + b) * D_ + ak];
        const float* src = key_in + ksr * BD + b * D_ + kkk;
        kv0 = *(const float4*)src;       kv1 = *(const float4*)(src + 4);
        kv2 = *(const float4*)(src + 8); kv3 = *(const float4*)(src + 12);
    }
    #pragma unroll 1
    for (int k0 = 0; k0 < D_; k0 += 32) {
        short* as_ = As + ((k0 >> 5) & 1) * (32 * 40);
        short* ks_ = Ks + ((k0 >> 5) & 1) * (128 * 40);
        const int kn = (k0 + 32 < D_) ? k0 + 32 : 0;
        uint2 nav = *(const uint2*)&qt_ws[((mh0 + ar) * B_ + b) * D_ + kn + ak];
        const float* src = key_in + ksr * BD + b * D_ + kn + kkk;
        float4 nk0 = *(const float4*)src,       nk1 = *(const float4*)(src + 4);
        float4 nk2 = *(const float4*)(src + 8), nk3 = *(const float4*)(src + 12);
        __builtin_amdgcn_sched_barrier(0);

        *(uint2*)&as_[ar * 40 + ak] = av;
        pack8(kv0, kv1, (uint4*)&ks_[ksr * 40 + kkk]);
        pack8(kv2, kv3, (uint4*)&ks_[ksr * 40 + kkk + 8]);
        lds_sync();
        bf16x8 a = *(const bf16x8*)&as_[(16 * wr + c16) * 40 + koffs];
        #pragma unroll
        for (int t = 0; t < 4; ++t) {
            bf16x8 kf = *(const bf16x8*)&ks_[(64 * wc + 16 * t + c16) * 40 + koffs];
            acc[t] = __builtin_amdgcn_mfma_f32_16x16x32_bf16(a, kf, acc[t], 0, 0, 0);
        }
        av = nav; kv0 = nk0; kv1 = nk1; kv2 = nk2; kv3 = nk3;
    }
    #pragma unroll
    for (int t = 0; t < 4; ++t)
        #pragma unroll
        for (int r = 0; r < 4; ++r) {
            int row = 16 * wr + (lane >> 4) * 4 + r;
            int col = 64 * wc + 16 * t + c16;
            scs[row * 132 + col] = acc[t][r] * 0.125f;
        }
    __syncthreads();

    // ---- softmax: 8 threads per mh-row ----
    {
        int row = tid >> 3, sub = tid & 7;
        float mx = -1e30f;
        #pragma unroll
        for (int i = 0; i < 16; ++i) mx = fmaxf(mx, scs[row * 132 + sub + 8 * i]);
        mx = fmaxf(mx, __shfl_xor(mx, 1));
        mx = fmaxf(mx, __shfl_xor(mx, 2));
        mx = fmaxf(mx, __shfl_xor(mx, 4));
        float e[16], sm = 0.f;
        #pragma unroll
        for (int i = 0; i < 16; ++i) { e[i] = __expf(scs[row * 132 + sub + 8 * i] - mx); sm += e[i]; }
        sm += __shfl_xor(sm, 1);
        sm += __shfl_xor(sm, 2);
        sm += __shfl_xor(sm, 4);
        float rinv = 1.0f / sm;
        #pragma unroll
        for (int i = 0; i < 16; ++i)
            wbuf[row * 136 + sub + 8 * i] = (short)f2bf(e[i] * rinv);
    }
    __syncthreads();

    // ---- phase 2: v~ GEMM, out [32 mh x 512 k], K = s = 128 ----
    f32x4 vacc[16] = {};
    const int hi = tid >> 6;
    #pragma unroll 1
    for (int s0 = 0; s0 < S_; s0 += 32) {
        #pragma unroll
        for (int c = 0; c < 8; ++c) {   // transposed value staging: Vs[n][ss]
            int n = lane + 64 * c;
            union { ushort u[8]; uint4 v; } tv;
            #pragma unroll
            for (int j = 0; j < 8; ++j)
                tv.u[j] = f2bf(value_in[(s0 + hi * 8 + j) * BD + b * D_ + n]);
            *(uint4*)&Vs[n * 40 + hi * 8] = tv.v;
        }
        __syncthreads();
        bf16x8 a = *(const bf16x8*)&wbuf[(16 * wr + c16) * 136 + s0 + koffs];
        #pragma unroll
        for (int t = 0; t < 16; ++t) {
            bf16x8 vf = *(const bf16x8*)&Vs[(256 * wc + 16 * t + c16) * 40 + koffs];
            vacc[t] = __builtin_amdgcn_mfma_f32_16x16x32_bf16(a, vf, vacc[t], 0, 0, 0);
        }
        __syncthreads();
    }
    #pragma unroll
    for (int t = 0; t < 16; ++t)
        #pragma unroll
        for (int r = 0; r < 4; ++r) {
            int row = 16 * wr + (lane >> 4) * 4 + r;
            int col = 256 * wc + 16 * t + c16;
            vt_ws[((mh0 + row) * B_ + b) * D_ + col] = f2bf(vacc[t][r]);
        }
}

// ---------------------------------------------------------------------------
// Kernel 4: ao[m,b,h*64+d'] = v~[mh,b,:].Wv[m][:,h*64+d'] + bv. grid (H, M).
// ---------------------------------------------------------------------------
__global__ __launch_bounds__(256) void k_aoproj(const ushort* __restrict__ vt_ws,
                                                const float* __restrict__ Wv,
                                                const float* __restrict__ bv,
                                                ushort* __restrict__ ao_ws)
{
    __shared__ __align__(16) short Xs[2 * 64 * 40];
    __shared__ __align__(16) short Ws[2 * 64 * 40];
    const int h = blockIdx.x, m = blockIdx.y;
    const int mh = m * H_ + h;
    f32x4 acc[4] = {};
    gemm64_bw(vt_ws + mh * B_ * D_, D_, Wv + m * D_ * D_ + h * HD_, D_, D_, Xs, Ws, acc);
    const int lane = threadIdx.x & 63, wv = threadIdx.x >> 6;
    #pragma unroll
    for (int t = 0; t < 4; ++t)
        #pragma unroll
        for (int r = 0; r < 4; ++r) {
            int row = 16 * wv + (lane >> 4) * 4 + r;         // b
            int col = 16 * t + (lane & 15);                  // d' in [0,64)
            ao_ws[(m * B_ + row) * D_ + h * HD_ + col] =
                f2bf(acc[t][r] + bv[m * D_ + h * HD_ + col]);
        }
}

// ---------------------------------------------------------------------------
// Kernel 5: attn_out = ao @ Wo + bo; x = relu([attn_out, prev_state]) -> x_ws
// grid (D/64, M)
// ---------------------------------------------------------------------------
__global__ __launch_bounds__(256) void k_oproj(const ushort* __restrict__ ao_ws,
                                               const float* __restrict__ Wo,
                                               const float* __restrict__ bo,
                                               const float* __restrict__ prev_state,
                                               ushort* __restrict__ x_ws)
{
    __shared__ __align__(16) short Xs[2 * 64 * 40];
    __shared__ __align__(16) short Ws[2 * 64 * 40];
    const int cb = blockIdx.x, m = blockIdx.y;
    #pragma unroll
    for (int e = 0; e < 2; ++e) {
        int idx = threadIdx.x + e * 256;
        int row = idx >> 3, koff = (idx & 7) * 8;
        const float* pp = prev_state + (m * B_ + row) * D_ + cb * 64 + koff;
        float4 a = *(const float4*)pp, b = *(const float4*)(pp + 4);
        a.x = fmaxf(a.x, 0.f); a.y = fmaxf(a.y, 0.f); a.z = fmaxf(a.z, 0.f); a.w = fmaxf(a.w, 0.f);
        b.x = fmaxf(b.x, 0.f); b.y = fmaxf(b.y, 0.f); b.z = fmaxf(b.z, 0.f); b.w = fmaxf(b.w, 0.f);
        pack8(a, b, (uint4*)&x_ws[(m * B_ + row) * (2 * D_) + D_ + cb * 64 + koff]);
    }
    f32x4 acc[4] = {};
    gemm64_bw(ao_ws + m * B_ * D_, D_, Wo + m * D_ * D_ + cb * 64, D_, D_, Xs, Ws, acc);
    const int lane = threadIdx.x & 63, wv = threadIdx.x >> 6;
    #pragma unroll
    for (int t = 0; t < 4; ++t)
        #pragma unroll
        for (int r = 0; r < 4; ++r) {
            int row = 16 * wv + (lane >> 4) * 4 + r;
            int col = cb * 64 + 16 * t + (lane & 15);
            float v = fmaxf(acc[t][r] + bo[m * D_ + col], 0.0f);
            x_ws[(m * B_ + row) * (2 * D_) + col] = f2bf(v);
        }
}

// ---------------------------------------------------------------------------
// Kernel 6: h = relu(x@W1+b1), hg = relu(x@Wg1+bg1) fused. Double-buffered +
// prefetched. grid (FF/64, M, 4 g)
// ---------------------------------------------------------------------------
__global__ __launch_bounds__(256) void k_mlp1(const ushort* __restrict__ x_ws,
                                              const float* __restrict__ W1,
                                              const float* __restrict__ b1,
                                              const float* __restrict__ Wg1,
                                              const float* __restrict__ bg1,
                                              ushort* __restrict__ h_ws,
                                              ushort* __restrict__ hg_ws)
{
    __shared__ __align__(16) short Xs[2 * 64 * 40];
    __shared__ __align__(16) short Wa[2 * 64 * 40];
    __shared__ __align__(16) short Wb[2 * 64 * 40];
    const int cb = blockIdx.x, m = blockIdx.y, g = blockIdx.z;
    const int gm = g * M_ + m;
    const float* WA = W1 + gm * 2 * D_ * FF_ + cb * 64;
    const float* WB = Wg1 + gm * 2 * D_ * FF_ + cb * 64;
    const ushort* X = x_ws + m * B_ * 2 * D_;
    const int tid = threadIdx.x, lane = tid & 63, wv = tid >> 6;
    const int c16 = lane & 15, koffs = (lane >> 4) * 8;
    const int xr = tid >> 2, xk = (tid & 3) * 8;
    const int wn = tid & 63, wk = (tid >> 6) * 8;
    f32x4 acc1[4] = {}, acc2[4] = {};

    uint4 xv; float w1f[8], w2f[8];
    {
        xv = *(const uint4*)&X[xr * (2 * D_) + xk];
        const float* wp1 = WA + wk * FF_ + wn;
        const float* wp2 = WB + wk * FF_ + wn;
        #pragma unroll
        for (int j = 0; j < 8; ++j) { w1f[j] = wp1[j * FF_]; w2f[j] = wp2[j * FF_]; }
    }
    #pragma unroll 1
    for (int k0 = 0; k0 < 2 * D_; k0 += 32) {
        short* xs = Xs + ((k0 >> 5) & 1) * 2560;
        short* wa = Wa + ((k0 >> 5) & 1) * 2560;
        short* wb = Wb + ((k0 >> 5) & 1) * 2560;
        const int kn = (k0 + 32 < 2 * D_) ? k0 + 32 : 0;
        uint4 nxv = *(const uint4*)&X[xr * (2 * D_) + kn + xk];
        float nw1[8], nw2[8];
        const float* wp1 = WA + (kn + wk) * FF_ + wn;
        const float* wp2 = WB + (kn + wk) * FF_ + wn;
        #pragma unroll
        for (int j = 0; j < 8; ++j) { nw1[j] = wp1[j * FF_]; nw2[j] = wp2[j * FF_]; }
        __builtin_amdgcn_sched_barrier(0);

        *(uint4*)&xs[xr * 40 + xk] = xv;
        union { ushort u[8]; uint4 v; } t1, t2;
        #pragma unroll
        for (int j = 0; j < 8; ++j) { t1.u[j] = f2bf(w1f[j]); t2.u[j] = f2bf(w2f[j]); }
        *(uint4*)&wa[wn * 40 + wk] = t1.v;
        *(uint4*)&wb[wn * 40 + wk] = t2.v;
        lds_sync();
        bf16x8 a = *(const bf16x8*)&xs[(16 * wv + c16) * 40 + koffs];
        #pragma unroll
        for (int t = 0; t < 4; ++t) {
            bf16x8 f1 = *(const bf16x8*)&wa[(16 * t + c16) * 40 + koffs];
            bf16x8 f2 = *(const bf16x8*)&wb[(16 * t + c16) * 40 + koffs];
            acc1[t] = __builtin_amdgcn_mfma_f32_16x16x32_bf16(a, f1, acc1[t], 0, 0, 0);
            acc2[t] = __builtin_amdgcn_mfma_f32_16x16x32_bf16(a, f2, acc2[t], 0, 0, 0);
        }
        xv = nxv;
        #pragma unroll
        for (int j = 0; j < 8; ++j) { w1f[j] = nw1[j]; w2f[j] = nw2[j]; }
    }
    #pragma unroll
    for (int t = 0; t < 4; ++t)
        #pragma unroll
        for (int r = 0; r < 4; ++r) {
            int row = 16 * wv + (lane >> 4) * 4 + r;
            int col = cb * 64 + 16 * t + c16;
            float v1 = fmaxf(acc1[t][r] + b1[gm * FF_ + col], 0.0f);
            float v2 = fmaxf(acc2[t][r] + bg1[gm * FF_ + col], 0.0f);
            h_ws [(gm * B_ + row) * FF_ + col] = f2bf(v1);
            hg_ws[(gm * B_ + row) * FF_ + col] = f2bf(v2);
        }
}

// ---------------------------------------------------------------------------
// Kernel 7: g = sigmoid(hg . Wg2 + bg2). grid (32 gm, 8 bblk); 8 rows/block,
// 32 lanes per row (was 32 blocks total -> only 32 CUs busy).
// ---------------------------------------------------------------------------
__global__ __launch_bounds__(256) void k_gate(const ushort* __restrict__ hg_ws,
                                              const float* __restrict__ Wg2,
                                              const float* __restrict__ bg2,
                                              float* __restrict__ g_ws)
{
    const int gm = blockIdx.x, bb = blockIdx.y;
    const int tid = threadIdx.x, b = bb * 8 + (tid >> 5), q = tid & 31;
    const ushort* hp = hg_ws + (gm * B_ + b) * FF_ + q * 32;
    const float* wp = Wg2 + gm * FF_ + q * 32;
    float s = 0.f;
    #pragma unroll
    for (int j = 0; j < 32; j += 8) {
        union { ushort u[8]; uint4 v; } a;
        a.v = *(const uint4*)&hp[j];
        float4 w0 = *(const float4*)&wp[j], w1 = *(const float4*)&wp[j + 4];
        s += bf2f(a.u[0]) * w0.x + bf2f(a.u[1]) * w0.y + bf2f(a.u[2]) * w0.z + bf2f(a.u[3]) * w0.w
           + bf2f(a.u[4]) * w1.x + bf2f(a.u[5]) * w1.y + bf2f(a.u[6]) * w1.z + bf2f(a.u[7]) * w1.w;
    }
    s += __shfl_xor(s, 1);
    s += __shfl_xor(s, 2);
    s += __shfl_xor(s, 4);
    s += __shfl_xor(s, 8);
    s += __shfl_xor(s, 16);
    if (q == 0)
        g_ws[gm * B_ + b] = 1.0f / (1.0f + __expf(-(s + bg2[gm])));
}

// ---------------------------------------------------------------------------
// Kernel 8: out = tanh(relu(h@W2+b2)); new = g*out + (1-g)*prev; permuted store.
// grid (D/64, M, 4 g). Output slot: g -> (g+1)&3.
// ---------------------------------------------------------------------------
__global__ __launch_bounds__(256) void k_mlp2(const ushort* __restrict__ h_ws,
                                              const float* __restrict__ W2,
                                              const float* __restrict__ b2,
                                              const float* __restrict__ g_ws,
                                              const float* __restrict__ prev_state,
                                              const float* __restrict__ prev_query,
                                              const float* __restrict__ prev_key,
                                              const float* __restrict__ prev_value,
                                              float* __restrict__ outp)
{
    __shared__ __align__(16) short Xs[2 * 64 * 40];
    __shared__ __align__(16) short Ws[2 * 64 * 40];
    const int cb = blockIdx.x, m = blockIdx.y, g = blockIdx.z;
    const int gm = g * M_ + m;
    f32x4 acc[4] = {};
    gemm64_bw(h_ws + gm * B_ * FF_, FF_, W2 + gm * FF_ * D_ + cb * 64, D_, FF_, Xs, Ws, acc);
    const float* prev = (g == 0) ? prev_query : (g == 1) ? prev_key
                      : (g == 2) ? prev_value : prev_state;
    const int slot = (g + 1) & 3;
    const int lane = threadIdx.x & 63, wv = threadIdx.x >> 6;
    #pragma unroll
    for (int t = 0; t < 4; ++t)
        #pragma unroll
        for (int r = 0; r < 4; ++r) {
            int row = 16 * wv + (lane >> 4) * 4 + r;
            int col = cb * 64 + 16 * t + (lane & 15);
            float v = tanhf(fmaxf(acc[t][r] + b2[gm * D_ + col], 0.0f));
            float gg = g_ws[gm * B_ + row];
            float pv = prev[(m * B_ + row) * D_ + col];
            outp[((slot * M_ + m) * B_ + row) * D_ + col] = gg * v + (1.0f - gg) * pv;
        }
}

// ---------------------------------------------------------------------------
extern "C" void kernel_launch(void* const* d_in, const int* in_sizes, int n_in,
                              void* d_out, int out_size, void* d_ws, size_t ws_size,
                              hipStream_t stream)
{
    (void)in_sizes; (void)n_in; (void)out_size; (void)ws_size;
    const float* prev_state = (const float*)d_in[0];
    const float* prev_query = (const float*)d_in[1];
    const float* prev_key   = (const float*)d_in[2];
    const float* prev_value = (const float*)d_in[3];
    const float* key_in     = (const float*)d_in[4];
    const float* value_in   = (const float*)d_in[5];
    const float* Wq  = (const float*)d_in[6];
    const float* bq  = (const float*)d_in[7];
    const float* Wk  = (const float*)d_in[8];
    const float* Wv  = (const float*)d_in[10];
    const float* bv  = (const float*)d_in[11];
    const float* Wo  = (const float*)d_in[12];
    const float* bo  = (const float*)d_in[13];
    const float* W1  = (const float*)d_in[14];
    const float* b1  = (const float*)d_in[15];
    const float* W2  = (const float*)d_in[16];
    const float* b2  = (const float*)d_in[17];
    const float* Wg1 = (const float*)d_in[18];
    const float* bg1 = (const float*)d_in[19];
    const float* Wg2 = (const float*)d_in[20];
    const float* bg2 = (const float*)d_in[21];
    float* outp = (float*)d_out;

    char* ws = (char*)d_ws;
    ushort* q_ws  = (ushort*)(ws);                        // 512 KB
    ushort* ao_ws = (ushort*)(ws + (512u << 10));         // 512 KB
    ushort* x_ws  = (ushort*)(ws + (1024u << 10));        // 1 MB
    ushort* qt_ws = (ushort*)(ws + (2048u << 10));        // 4 MB (later reused as h_ws)
    ushort* vt_ws = (ushort*)(ws + (6144u << 10));        // 4 MB (later reused as hg_ws)
    ushort* h_ws  = qt_ws;                                // overlay: qt dead after k_attn2
    ushort* hg_ws = vt_ws;                                // overlay: vt dead after k_aoproj
    float*  g_ws  = (float*) (ws + (10240u << 10));       // 8 KB

    k_qproj <<<dim3(8, 8), 256, 0, stream>>>(prev_query, Wq, bq, q_ws);
    k_qtilde<<<dim3(8, 8, 8), 256, 0, stream>>>(q_ws, Wk, qt_ws);
    k_attn2 <<<dim3(2, 64), 256, 0, stream>>>(key_in, value_in, qt_ws, vt_ws);
    k_aoproj<<<dim3(8, 8), 256, 0, stream>>>(vt_ws, Wv, bv, ao_ws);
    k_oproj <<<dim3(8, 8), 256, 0, stream>>>(ao_ws, Wo, bo, prev_state, x_ws);
    k_mlp1  <<<dim3(16, 8, 4), 256, 0, stream>>>(x_ws, W1, b1, Wg1, bg1, h_ws, hg_ws);
    k_gate  <<<dim3(32, 8), 256, 0, stream>>>(hg_ws, Wg2, bg2, g_ws);
    k_mlp2  <<<dim3(8, 8, 4), 256, 0, stream>>>(h_ws, W2, b2, g_ws,
                                                prev_state, prev_query, prev_key, prev_value, outp);
}

// Round 2
// 461.888 us; speedup vs baseline: 1.1279x; 1.0297x over previous
//
#include <hip/hip_runtime.h>

#define M_ 8
#define B_ 64
#define S_ 128
#define D_ 512
#define H_ 8
#define FF_ 1024
#define HD_ 64

typedef __bf16 bf16x8 __attribute__((ext_vector_type(8)));
typedef float f32x4 __attribute__((ext_vector_type(4)));

__device__ __forceinline__ float bf2f(ushort u) {
    union { unsigned int i; float f; } x; x.i = ((unsigned int)u) << 16; return x.f;
}
__device__ __forceinline__ ushort f2bf(float f) {
    union { unsigned int i; float f; } x; x.f = f;
    unsigned int i = x.i;
    return (ushort)((i + 0x7FFFu + ((i >> 16) & 1u)) >> 16);
}
__device__ __forceinline__ void pack8(const float4 a, const float4 b, uint4* dst) {
    union { ushort u[8]; uint4 v; } t;
    t.u[0] = f2bf(a.x); t.u[1] = f2bf(a.y); t.u[2] = f2bf(a.z); t.u[3] = f2bf(a.w);
    t.u[4] = f2bf(b.x); t.u[5] = f2bf(b.y); t.u[6] = f2bf(b.z); t.u[7] = f2bf(b.w);
    *dst = t.v;
}

// Barrier that does NOT drain vmcnt: LDS-visibility only. Prefetched global
// loads stay in flight across it.
__device__ __forceinline__ void lds_sync() {
    __builtin_amdgcn_sched_barrier(0);
    asm volatile("s_waitcnt lgkmcnt(0)" ::: "memory");
    __builtin_amdgcn_s_barrier();
    __builtin_amdgcn_sched_barrier(0);
}

// ---------------------------------------------------------------------------
// 512-thread split-K GEMM (64x64 output tile). Wave-group kg = tid>>8 handles
// K-half [kg*K/2, (kg+1)*K/2). Each group double-buffers its own LDS staging;
// partial f32 accs combined through LDS at the end (valid in kg=0 threads).
// Xs/Ws must each hold 2 groups * 2 bufs * 2560 shorts.
// ---------------------------------------------------------------------------
__device__ __forceinline__ void gemm64_fw512(const float* __restrict__ X, int ldx,
                                             const float* __restrict__ Wc, int ldw,
                                             int K, short* Xs, short* Ws, f32x4* acc)
{
    const int tid = threadIdx.x;
    const int kg = tid >> 8, t = tid & 255;
    const int lane = t & 63, wv = t >> 6;
    const int c16 = lane & 15, koffs = (lane >> 4) * 8;
    const int xr = t >> 2, xk = (t & 3) * 8;
    const int wn = t & 63, wk = (t >> 6) * 8;
    const int K2 = K >> 1, kbase = kg * K2;
    short* Xg = Xs + kg * 2 * 2560;
    short* Wg = Ws + kg * 2 * 2560;
    float4 xa, xb; float wf[8];
    {
        const float* xp = X + xr * ldx + kbase + xk;
        xa = *(const float4*)xp; xb = *(const float4*)(xp + 4);
        const float* wp = Wc + (kbase + wk) * ldw + wn;
        #pragma unroll
        for (int j = 0; j < 8; ++j) wf[j] = wp[j * ldw];
    }
    #pragma unroll 1
    for (int k0 = 0; k0 < K2; k0 += 32) {
        short* xs = Xg + ((k0 >> 5) & 1) * 2560;
        short* ws = Wg + ((k0 >> 5) & 1) * 2560;
        const int kn = kbase + ((k0 + 32 < K2) ? k0 + 32 : 0);
        const float* xp = X + xr * ldx + kn + xk;
        float4 nxa = *(const float4*)xp, nxb = *(const float4*)(xp + 4);
        float nwf[8];
        const float* wp = Wc + (kn + wk) * ldw + wn;
        #pragma unroll
        for (int j = 0; j < 8; ++j) nwf[j] = wp[j * ldw];
        __builtin_amdgcn_sched_barrier(0);

        pack8(xa, xb, (uint4*)&xs[xr * 40 + xk]);
        union { ushort u[8]; uint4 v; } tw;
        #pragma unroll
        for (int j = 0; j < 8; ++j) tw.u[j] = f2bf(wf[j]);
        *(uint4*)&ws[wn * 40 + wk] = tw.v;
        lds_sync();
        bf16x8 a = *(const bf16x8*)&xs[(16 * wv + c16) * 40 + koffs];
        #pragma unroll
        for (int tt = 0; tt < 4; ++tt) {
            bf16x8 bfr = *(const bf16x8*)&ws[(16 * tt + c16) * 40 + koffs];
            acc[tt] = __builtin_amdgcn_mfma_f32_16x16x32_bf16(a, bfr, acc[tt], 0, 0, 0);
        }
        xa = nxa; xb = nxb;
        #pragma unroll
        for (int j = 0; j < 8; ++j) wf[j] = nwf[j];
    }
    __syncthreads();
    float* red = (float*)Xs;        // 16 KB needed; Xs region is 20.5 KB
    if (kg == 1) {
        #pragma unroll
        for (int tt = 0; tt < 4; ++tt) *(f32x4*)&red[(t * 4 + tt) * 4] = acc[tt];
    }
    __syncthreads();
    if (kg == 0) {
        #pragma unroll
        for (int tt = 0; tt < 4; ++tt) acc[tt] += *(const f32x4*)&red[(t * 4 + tt) * 4];
    }
}

__device__ __forceinline__ void gemm64_bw512(const ushort* __restrict__ X, int ldx,
                                             const float* __restrict__ Wc, int ldw,
                                             int K, short* Xs, short* Ws, f32x4* acc)
{
    const int tid = threadIdx.x;
    const int kg = tid >> 8, t = tid & 255;
    const int lane = t & 63, wv = t >> 6;
    const int c16 = lane & 15, koffs = (lane >> 4) * 8;
    const int xr = t >> 2, xk = (t & 3) * 8;
    const int wn = t & 63, wk = (t >> 6) * 8;
    const int K2 = K >> 1, kbase = kg * K2;
    short* Xg = Xs + kg * 2 * 2560;
    short* Wg = Ws + kg * 2 * 2560;
    uint4 xv; float wf[8];
    {
        xv = *(const uint4*)&X[xr * ldx + kbase + xk];
        const float* wp = Wc + (kbase + wk) * ldw + wn;
        #pragma unroll
        for (int j = 0; j < 8; ++j) wf[j] = wp[j * ldw];
    }
    #pragma unroll 1
    for (int k0 = 0; k0 < K2; k0 += 32) {
        short* xs = Xg + ((k0 >> 5) & 1) * 2560;
        short* ws = Wg + ((k0 >> 5) & 1) * 2560;
        const int kn = kbase + ((k0 + 32 < K2) ? k0 + 32 : 0);
        uint4 nxv = *(const uint4*)&X[xr * ldx + kn + xk];
        float nwf[8];
        const float* wp = Wc + (kn + wk) * ldw + wn;
        #pragma unroll
        for (int j = 0; j < 8; ++j) nwf[j] = wp[j * ldw];
        __builtin_amdgcn_sched_barrier(0);

        *(uint4*)&xs[xr * 40 + xk] = xv;
        union { ushort u[8]; uint4 v; } tw;
        #pragma unroll
        for (int j = 0; j < 8; ++j) tw.u[j] = f2bf(wf[j]);
        *(uint4*)&ws[wn * 40 + wk] = tw.v;
        lds_sync();
        bf16x8 a = *(const bf16x8*)&xs[(16 * wv + c16) * 40 + koffs];
        #pragma unroll
        for (int tt = 0; tt < 4; ++tt) {
            bf16x8 bfr = *(const bf16x8*)&ws[(16 * tt + c16) * 40 + koffs];
            acc[tt] = __builtin_amdgcn_mfma_f32_16x16x32_bf16(a, bfr, acc[tt], 0, 0, 0);
        }
        xv = nxv;
        #pragma unroll
        for (int j = 0; j < 8; ++j) wf[j] = nwf[j];
    }
    __syncthreads();
    float* red = (float*)Xs;
    if (kg == 1) {
        #pragma unroll
        for (int tt = 0; tt < 4; ++tt) *(f32x4*)&red[(t * 4 + tt) * 4] = acc[tt];
    }
    __syncthreads();
    if (kg == 0) {
        #pragma unroll
        for (int tt = 0; tt < 4; ++tt) acc[tt] += *(const f32x4*)&red[(t * 4 + tt) * 4];
    }
}

// ---------------------------------------------------------------------------
// Kernel 1: q = prev_query @ Wq + bq. grid (D/64, M), 512 thr.
// ---------------------------------------------------------------------------
__global__ __launch_bounds__(512, 4) void k_qproj(const float* __restrict__ prev_query,
                                                  const float* __restrict__ Wq,
                                                  const float* __restrict__ bq,
                                                  ushort* __restrict__ q_ws)
{
    __shared__ __align__(16) short Xs[2 * 2 * 2560];
    __shared__ __align__(16) short Ws[2 * 2 * 2560];
    const int cb = blockIdx.x, m = blockIdx.y;
    f32x4 acc[4] = {};
    gemm64_fw512(prev_query + m * B_ * D_, D_, Wq + m * D_ * D_ + cb * 64, D_, D_, Xs, Ws, acc);
    const int tid = threadIdx.x;
    if (tid < 256) {
        const int lane = tid & 63, wv = tid >> 6;
        #pragma unroll
        for (int t = 0; t < 4; ++t)
            #pragma unroll
            for (int r = 0; r < 4; ++r) {
                int row = 16 * wv + (lane >> 4) * 4 + r;
                int col = cb * 64 + 16 * t + (lane & 15);
                q_ws[(m * B_ + row) * D_ + col] = f2bf(acc[t][r] + bq[m * D_ + col]);
            }
    }
}

// ---------------------------------------------------------------------------
// Kernel 2: q~[mh, b, k] = qh . Wk^T (per head). grid (8 kb, H, M), 256 thr.
// ---------------------------------------------------------------------------
__global__ __launch_bounds__(256) void k_qtilde(const ushort* __restrict__ q_ws,
                                                const float* __restrict__ Wk,
                                                ushort* __restrict__ qt_ws)
{
    const int kb = blockIdx.x, h = blockIdx.y, m = blockIdx.z;
    __shared__ __align__(16) short As[64 * 72];
    __shared__ __align__(16) short Ws[64 * 72];
    const int tid = threadIdx.x, lane = tid & 63, wv = tid >> 6;
    {   // stage A = qh [b=64][j=64]
        int r = lane, jj = wv * 16;
        const ushort* src = q_ws + (m * B_ + r) * D_ + h * HD_ + jj;
        *(uint4*)&As[r * 72 + jj]     = *(const uint4*)src;
        *(uint4*)&As[r * 72 + jj + 8] = *(const uint4*)(src + 8);
    }
    {   // stage B[j][n=k] = Wk[m][kb*64+n, h*64+j]
        int n = lane, jj = wv * 16;
        const float* src = Wk + m * D_ * D_ + (kb * 64 + n) * D_ + h * HD_ + jj;
        pack8(*(const float4*)src, *(const float4*)(src + 4), (uint4*)&Ws[n * 72 + jj]);
        pack8(*(const float4*)(src + 8), *(const float4*)(src + 12), (uint4*)&Ws[n * 72 + jj + 8]);
    }
    __syncthreads();
    const int c16 = lane & 15, koffs = (lane >> 4) * 8;
    f32x4 acc[4] = {};
    #pragma unroll
    for (int j0 = 0; j0 < 64; j0 += 32) {
        bf16x8 a = *(const bf16x8*)&As[(16 * wv + c16) * 72 + j0 + koffs];
        #pragma unroll
        for (int t = 0; t < 4; ++t) {
            bf16x8 bfr = *(const bf16x8*)&Ws[(16 * t + c16) * 72 + j0 + koffs];
            acc[t] = __builtin_amdgcn_mfma_f32_16x16x32_bf16(a, bfr, acc[t], 0, 0, 0);
        }
    }
    const int mh = m * H_ + h;
    #pragma unroll
    for (int t = 0; t < 4; ++t)
        #pragma unroll
        for (int r = 0; r < 4; ++r) {
            int row = 16 * wv + (lane >> 4) * 4 + r;     // b
            int col = kb * 64 + 16 * t + (lane & 15);    // k
            qt_ws[(mh * B_ + row) * D_ + col] = f2bf(acc[t][r]);
        }
}

// ---------------------------------------------------------------------------
// Kernel 3: per (b, half): scores -> softmax -> v~. grid (2, B), 256 thr.
// ---------------------------------------------------------------------------
__global__ __launch_bounds__(256) void k_attn2(const float* __restrict__ key_in,
                                               const float* __restrict__ value_in,
                                               const ushort* __restrict__ qt_ws,
                                               ushort* __restrict__ vt_ws)
{
    const int half = blockIdx.x, b = blockIdx.y;
    const int mh0 = half * 32;
    __shared__ __align__(16) short As[2 * 32 * 40];
    __shared__ __align__(16) short Ks[2 * 128 * 40];
    __shared__ __align__(16) short Vs[512 * 40];
    __shared__ float scs[32 * 132];
    __shared__ __align__(16) short wbuf[32 * 136];
    const int tid = threadIdx.x, lane = tid & 63, wv = tid >> 6;
    const int c16 = lane & 15, koffs = (lane >> 4) * 8;
    const int wr = wv >> 1, wc = wv & 1;
    const int BD = B_ * D_;

    // ---- phase 1: scores GEMM, out [32 mh x 128 s], K = 512 ----
    f32x4 acc[4] = {};
    const int ar = tid >> 3, ak = (tid & 7) * 4;
    const int ksr = tid >> 1, kkk = (tid & 1) * 16;
    uint2 av; float4 kv0, kv1, kv2, kv3;
    {
        av = *(const uint2*)&qt_ws[((mh0 + ar) * B_ + b) * D_ + ak];
        const float* src = key_in + ksr * BD + b * D_ + kkk;
        kv0 = *(const float4*)src;       kv1 = *(const float4*)(src + 4);
        kv2 = *(const float4*)(src + 8); kv3 = *(const float4*)(src + 12);
    }
    #pragma unroll 1
    for (int k0 = 0; k0 < D_; k0 += 32) {
        short* as_ = As + ((k0 >> 5) & 1) * (32 * 40);
        short* ks_ = Ks + ((k0 >> 5) & 1) * (128 * 40);
        const int kn = (k0 + 32 < D_) ? k0 + 32 : 0;
        uint2 nav = *(const uint2*)&qt_ws[((mh0 + ar) * B_ + b) * D_ + kn + ak];
        const float* src = key_in + ksr * BD + b * D_ + kn + kkk;
        float4 nk0 = *(const float4*)src,       nk1 = *(const float4*)(src + 4);
        float4 nk2 = *(const float4*)(src + 8), nk3 = *(const float4*)(src + 12);
        __builtin_amdgcn_sched_barrier(0);

        *(uint2*)&as_[ar * 40 + ak] = av;
        pack8(kv0, kv1, (uint4*)&ks_[ksr * 40 + kkk]);
        pack8(kv2, kv3, (uint4*)&ks_[ksr * 40 + kkk + 8]);
        lds_sync();
        bf16x8 a = *(const bf16x8*)&as_[(16 * wr + c16) * 40 + koffs];
        #pragma unroll
        for (int t = 0; t < 4; ++t) {
            bf16x8 kf = *(const bf16x8*)&ks_[(64 * wc + 16 * t + c16) * 40 + koffs];
            acc[t] = __builtin_amdgcn_mfma_f32_16x16x32_bf16(a, kf, acc[t], 0, 0, 0);
        }
        av = nav; kv0 = nk0; kv1 = nk1; kv2 = nk2; kv3 = nk3;
    }
    #pragma unroll
    for (int t = 0; t < 4; ++t)
        #pragma unroll
        for (int r = 0; r < 4; ++r) {
            int row = 16 * wr + (lane >> 4) * 4 + r;
            int col = 64 * wc + 16 * t + c16;
            scs[row * 132 + col] = acc[t][r] * 0.125f;
        }
    __syncthreads();

    // ---- softmax: 8 threads per mh-row ----
    {
        int row = tid >> 3, sub = tid & 7;
        float mx = -1e30f;
        #pragma unroll
        for (int i = 0; i < 16; ++i) mx = fmaxf(mx, scs[row * 132 + sub + 8 * i]);
        mx = fmaxf(mx, __shfl_xor(mx, 1));
        mx = fmaxf(mx, __shfl_xor(mx, 2));
        mx = fmaxf(mx, __shfl_xor(mx, 4));
        float e[16], sm = 0.f;
        #pragma unroll
        for (int i = 0; i < 16; ++i) { e[i] = __expf(scs[row * 132 + sub + 8 * i] - mx); sm += e[i]; }
        sm += __shfl_xor(sm, 1);
        sm += __shfl_xor(sm, 2);
        sm += __shfl_xor(sm, 4);
        float rinv = 1.0f / sm;
        #pragma unroll
        for (int i = 0; i < 16; ++i)
            wbuf[row * 136 + sub + 8 * i] = (short)f2bf(e[i] * rinv);
    }
    __syncthreads();

    // ---- phase 2: v~ GEMM, out [32 mh x 512 k], K = s = 128 ----
    f32x4 vacc[16] = {};
    const int hi = tid >> 6;
    #pragma unroll 1
    for (int s0 = 0; s0 < S_; s0 += 32) {
        #pragma unroll
        for (int c = 0; c < 8; ++c) {   // transposed value staging: Vs[n][ss]
            int n = lane + 64 * c;
            union { ushort u[8]; uint4 v; } tv;
            #pragma unroll
            for (int j = 0; j < 8; ++j)
                tv.u[j] = f2bf(value_in[(s0 + hi * 8 + j) * BD + b * D_ + n]);
            *(uint4*)&Vs[n * 40 + hi * 8] = tv.v;
        }
        __syncthreads();
        bf16x8 a = *(const bf16x8*)&wbuf[(16 * wr + c16) * 136 + s0 + koffs];
        #pragma unroll
        for (int t = 0; t < 16; ++t) {
            bf16x8 vf = *(const bf16x8*)&Vs[(256 * wc + 16 * t + c16) * 40 + koffs];
            vacc[t] = __builtin_amdgcn_mfma_f32_16x16x32_bf16(a, vf, vacc[t], 0, 0, 0);
        }
        __syncthreads();
    }
    #pragma unroll
    for (int t = 0; t < 16; ++t)
        #pragma unroll
        for (int r = 0; r < 4; ++r) {
            int row = 16 * wr + (lane >> 4) * 4 + r;
            int col = 256 * wc + 16 * t + c16;
            vt_ws[((mh0 + row) * B_ + b) * D_ + col] = f2bf(vacc[t][r]);
        }
}

// ---------------------------------------------------------------------------
// Kernel 4: ao = v~ . Wv + bv (per head cols). grid (H, M), 512 thr.
// ---------------------------------------------------------------------------
__global__ __launch_bounds__(512, 4) void k_aoproj(const ushort* __restrict__ vt_ws,
                                                   const float* __restrict__ Wv,
                                                   const float* __restrict__ bv,
                                                   ushort* __restrict__ ao_ws)
{
    __shared__ __align__(16) short Xs[2 * 2 * 2560];
    __shared__ __align__(16) short Ws[2 * 2 * 2560];
    const int h = blockIdx.x, m = blockIdx.y;
    const int mh = m * H_ + h;
    f32x4 acc[4] = {};
    gemm64_bw512(vt_ws + mh * B_ * D_, D_, Wv + m * D_ * D_ + h * HD_, D_, D_, Xs, Ws, acc);
    const int tid = threadIdx.x;
    if (tid < 256) {
        const int lane = tid & 63, wv = tid >> 6;
        #pragma unroll
        for (int t = 0; t < 4; ++t)
            #pragma unroll
            for (int r = 0; r < 4; ++r) {
                int row = 16 * wv + (lane >> 4) * 4 + r;         // b
                int col = 16 * t + (lane & 15);                  // d' in [0,64)
                ao_ws[(m * B_ + row) * D_ + h * HD_ + col] =
                    f2bf(acc[t][r] + bv[m * D_ + h * HD_ + col]);
            }
    }
}

// ---------------------------------------------------------------------------
// Kernel 5: attn_out = ao @ Wo + bo; x = relu([attn_out, prev_state]).
// grid (D/64, M), 512 thr.
// ---------------------------------------------------------------------------
__global__ __launch_bounds__(512, 4) void k_oproj(const ushort* __restrict__ ao_ws,
                                                  const float* __restrict__ Wo,
                                                  const float* __restrict__ bo,
                                                  const float* __restrict__ prev_state,
                                                  ushort* __restrict__ x_ws)
{
    __shared__ __align__(16) short Xs[2 * 2 * 2560];
    __shared__ __align__(16) short Ws[2 * 2 * 2560];
    const int cb = blockIdx.x, m = blockIdx.y;
    {
        int idx = threadIdx.x;                 // 512 units: 64 rows x 8 col-chunks
        int row = idx >> 3, koff = (idx & 7) * 8;
        const float* pp = prev_state + (m * B_ + row) * D_ + cb * 64 + koff;
        float4 a = *(const float4*)pp, b = *(const float4*)(pp + 4);
        a.x = fmaxf(a.x, 0.f); a.y = fmaxf(a.y, 0.f); a.z = fmaxf(a.z, 0.f); a.w = fmaxf(a.w, 0.f);
        b.x = fmaxf(b.x, 0.f); b.y = fmaxf(b.y, 0.f); b.z = fmaxf(b.z, 0.f); b.w = fmaxf(b.w, 0.f);
        pack8(a, b, (uint4*)&x_ws[(m * B_ + row) * (2 * D_) + D_ + cb * 64 + koff]);
    }
    f32x4 acc[4] = {};
    gemm64_bw512(ao_ws + m * B_ * D_, D_, Wo + m * D_ * D_ + cb * 64, D_, D_, Xs, Ws, acc);
    const int tid = threadIdx.x;
    if (tid < 256) {
        const int lane = tid & 63, wv = tid >> 6;
        #pragma unroll
        for (int t = 0; t < 4; ++t)
            #pragma unroll
            for (int r = 0; r < 4; ++r) {
                int row = 16 * wv + (lane >> 4) * 4 + r;
                int col = cb * 64 + 16 * t + (lane & 15);
                float v = fmaxf(acc[t][r] + bo[m * D_ + col], 0.0f);
                x_ws[(m * B_ + row) * (2 * D_) + col] = f2bf(v);
            }
    }
}

// ---------------------------------------------------------------------------
// Kernel 6: h = relu(x@W1+b1), hg = relu(x@Wg1+bg1). 512 thr: wave-group 0
// owns W1->h, group 1 owns Wg1->hg (split-matrix, full K each, no reduction).
// X tile staged once by group 0, shared. grid (FF/64, M, 4 g).
// ---------------------------------------------------------------------------
__global__ __launch_bounds__(512, 4) void k_mlp1(const ushort* __restrict__ x_ws,
                                                 const float* __restrict__ W1,
                                                 const float* __restrict__ b1,
                                                 const float* __restrict__ Wg1,
                                                 const float* __restrict__ bg1,
                                                 ushort* __restrict__ h_ws,
                                                 ushort* __restrict__ hg_ws)
{
    __shared__ __align__(16) short smem[6 * 2560];  // Xs[2 buf] | W(kg=0)[2 buf] | W(kg=1)[2 buf]
    const int cb = blockIdx.x, m = blockIdx.y, g = blockIdx.z;
    const int gm = g * M_ + m;
    const int tid = threadIdx.x;
    const int kg = tid >> 8, t = tid & 255;
    const int lane = t & 63, wv = t >> 6;
    const int c16 = lane & 15, koffs = (lane >> 4) * 8;
    const int xr = t >> 2, xk = (t & 3) * 8;
    const int wn = t & 63, wk = (t >> 6) * 8;
    const float* Wm = (kg == 0 ? W1 : Wg1) + gm * 2 * D_ * FF_ + cb * 64;
    const ushort* X = x_ws + m * B_ * 2 * D_;
    short* Xs = smem;
    short* Wg = smem + 2 * 2560 + kg * 2 * 2560;
    f32x4 acc[4] = {};

    uint4 xv = {};
    float wf[8];
    {
        if (kg == 0) xv = *(const uint4*)&X[xr * (2 * D_) + xk];
        const float* wp = Wm + wk * FF_ + wn;
        #pragma unroll
        for (int j = 0; j < 8; ++j) wf[j] = wp[j * FF_];
    }
    #pragma unroll 1
    for (int k0 = 0; k0 < 2 * D_; k0 += 32) {
        short* xs = Xs + ((k0 >> 5) & 1) * 2560;
        short* ws = Wg + ((k0 >> 5) & 1) * 2560;
        const int kn = (k0 + 32 < 2 * D_) ? k0 + 32 : 0;
        uint4 nxv = {};
        if (kg == 0) nxv = *(const uint4*)&X[xr * (2 * D_) + kn + xk];
        float nwf[8];
        const float* wp = Wm + (kn + wk) * FF_ + wn;
        #pragma unroll
        for (int j = 0; j < 8; ++j) nwf[j] = wp[j * FF_];
        __builtin_amdgcn_sched_barrier(0);

        if (kg == 0) *(uint4*)&xs[xr * 40 + xk] = xv;
        union { ushort u[8]; uint4 v; } tw;
        #pragma unroll
        for (int j = 0; j < 8; ++j) tw.u[j] = f2bf(wf[j]);
        *(uint4*)&ws[wn * 40 + wk] = tw.v;
        lds_sync();
        bf16x8 a = *(const bf16x8*)&xs[(16 * wv + c16) * 40 + koffs];
        #pragma unroll
        for (int tt = 0; tt < 4; ++tt) {
            bf16x8 bfr = *(const bf16x8*)&ws[(16 * tt + c16) * 40 + koffs];
            acc[tt] = __builtin_amdgcn_mfma_f32_16x16x32_bf16(a, bfr, acc[tt], 0, 0, 0);
        }
        xv = nxv;
        #pragma unroll
        for (int j = 0; j < 8; ++j) wf[j] = nwf[j];
    }
    const float* bias = (kg == 0) ? b1 : bg1;
    ushort* dst = (kg == 0) ? h_ws : hg_ws;
    #pragma unroll
    for (int tt = 0; tt < 4; ++tt)
        #pragma unroll
        for (int r = 0; r < 4; ++r) {
            int row = 16 * wv + (lane >> 4) * 4 + r;
            int col = cb * 64 + 16 * tt + c16;
            float v = fmaxf(acc[tt][r] + bias[gm * FF_ + col], 0.0f);
            dst[(gm * B_ + row) * FF_ + col] = f2bf(v);
        }
}

// ---------------------------------------------------------------------------
// Kernel 7: g = sigmoid(hg . Wg2 + bg2). grid (32 gm, 8 bblk), 256 thr.
// ---------------------------------------------------------------------------
__global__ __launch_bounds__(256) void k_gate(const ushort* __restrict__ hg_ws,
                                              const float* __restrict__ Wg2,
                                              const float* __restrict__ bg2,
                                              float* __restrict__ g_ws)
{
    const int gm = blockIdx.x, bb = blockIdx.y;
    const int tid = threadIdx.x, b = bb * 8 + (tid >> 5), q = tid & 31;
    const ushort* hp = hg_ws + (gm * B_ + b) * FF_ + q * 32;
    const float* wp = Wg2 + gm * FF_ + q * 32;
    float s = 0.f;
    #pragma unroll
    for (int j = 0; j < 32; j += 8) {
        union { ushort u[8]; uint4 v; } a;
        a.v = *(const uint4*)&hp[j];
        float4 w0 = *(const float4*)&wp[j], w1 = *(const float4*)&wp[j + 4];
        s += bf2f(a.u[0]) * w0.x + bf2f(a.u[1]) * w0.y + bf2f(a.u[2]) * w0.z + bf2f(a.u[3]) * w0.w
           + bf2f(a.u[4]) * w1.x + bf2f(a.u[5]) * w1.y + bf2f(a.u[6]) * w1.z + bf2f(a.u[7]) * w1.w;
    }
    s += __shfl_xor(s, 1);
    s += __shfl_xor(s, 2);
    s += __shfl_xor(s, 4);
    s += __shfl_xor(s, 8);
    s += __shfl_xor(s, 16);
    if (q == 0)
        g_ws[gm * B_ + b] = 1.0f / (1.0f + __expf(-(s + bg2[gm])));
}

// ---------------------------------------------------------------------------
// Kernel 8: out = tanh(relu(h@W2+b2)); new = g*out + (1-g)*prev. 512 thr.
// grid (D/64, M, 4 g). Output slot: g -> (g+1)&3.
// ---------------------------------------------------------------------------
__global__ __launch_bounds__(512, 4) void k_mlp2(const ushort* __restrict__ h_ws,
                                                 const float* __restrict__ W2,
                                                 const float* __restrict__ b2,
                                                 const float* __restrict__ g_ws,
                                                 const float* __restrict__ prev_state,
                                                 const float* __restrict__ prev_query,
                                                 const float* __restrict__ prev_key,
                                                 const float* __restrict__ prev_value,
                                                 float* __restrict__ outp)
{
    __shared__ __align__(16) short Xs[2 * 2 * 2560];
    __shared__ __align__(16) short Ws[2 * 2 * 2560];
    const int cb = blockIdx.x, m = blockIdx.y, g = blockIdx.z;
    const int gm = g * M_ + m;
    f32x4 acc[4] = {};
    gemm64_bw512(h_ws + gm * B_ * FF_, FF_, W2 + gm * FF_ * D_ + cb * 64, D_, FF_, Xs, Ws, acc);
    const float* prev = (g == 0) ? prev_query : (g == 1) ? prev_key
                      : (g == 2) ? prev_value : prev_state;
    const int slot = (g + 1) & 3;
    const int tid = threadIdx.x;
    if (tid < 256) {
        const int lane = tid & 63, wv = tid >> 6;
        #pragma unroll
        for (int t = 0; t < 4; ++t)
            #pragma unroll
            for (int r = 0; r < 4; ++r) {
                int row = 16 * wv + (lane >> 4) * 4 + r;
                int col = cb * 64 + 16 * t + (lane & 15);
                float v = tanhf(fmaxf(acc[t][r] + b2[gm * D_ + col], 0.0f));
                float gg = g_ws[gm * B_ + row];
                float pv = prev[(m * B_ + row) * D_ + col];
                outp[((slot * M_ + m) * B_ + row) * D_ + col] = gg * v + (1.0f - gg) * pv;
            }
    }
}

// ---------------------------------------------------------------------------
extern "C" void kernel_launch(void* const* d_in, const int* in_sizes, int n_in,
                              void* d_out, int out_size, void* d_ws, size_t ws_size,
                              hipStream_t stream)
{
    (void)in_sizes; (void)n_in; (void)out_size; (void)ws_size;
    const float* prev_state = (const float*)d_in[0];
    const float* prev_query = (const float*)d_in[1];
    const float* prev_key   = (const float*)d_in[2];
    const float* prev_value = (const float*)d_in[3];
    const float* key_in     = (const float*)d_in[4];
    const float* value_in   = (const float*)d_in[5];
    const float* Wq  = (const float*)d_in[6];
    const float* bq  = (const float*)d_in[7];
    const float* Wk  = (const float*)d_in[8];
    const float* Wv  = (const float*)d_in[10];
    const float* bv  = (const float*)d_in[11];
    const float* Wo  = (const float*)d_in[12];
    const float* bo  = (const float*)d_in[13];
    const float* W1  = (const float*)d_in[14];
    const float* b1  = (const float*)d_in[15];
    const float* W2  = (const float*)d_in[16];
    const float* b2  = (const float*)d_in[17];
    const float* Wg1 = (const float*)d_in[18];
    const float* bg1 = (const float*)d_in[19];
    const float* Wg2 = (const float*)d_in[20];
    const float* bg2 = (const float*)d_in[21];
    float* outp = (float*)d_out;

    char* ws = (char*)d_ws;
    ushort* q_ws  = (ushort*)(ws);                        // 512 KB
    ushort* ao_ws = (ushort*)(ws + (512u << 10));         // 512 KB
    ushort* x_ws  = (ushort*)(ws + (1024u << 10));        // 1 MB
    ushort* qt_ws = (ushort*)(ws + (2048u << 10));        // 4 MB (later reused as h_ws)
    ushort* vt_ws = (ushort*)(ws + (6144u << 10));        // 4 MB (later reused as hg_ws)
    ushort* h_ws  = qt_ws;                                // overlay: qt dead after k_attn2
    ushort* hg_ws = vt_ws;                                // overlay: vt dead after k_aoproj
    float*  g_ws  = (float*) (ws + (10240u << 10));       // 8 KB

    k_qproj <<<dim3(8, 8), 512, 0, stream>>>(prev_query, Wq, bq, q_ws);
    k_qtilde<<<dim3(8, 8, 8), 256, 0, stream>>>(q_ws, Wk, qt_ws);
    k_attn2 <<<dim3(2, 64), 256, 0, stream>>>(key_in, value_in, qt_ws, vt_ws);
    k_aoproj<<<dim3(8, 8), 512, 0, stream>>>(vt_ws, Wv, bv, ao_ws);
    k_oproj <<<dim3(8, 8), 512, 0, stream>>>(ao_ws, Wo, bo, prev_state, x_ws);
    k_mlp1  <<<dim3(16, 8, 4), 512, 0, stream>>>(x_ws, W1, b1, Wg1, bg1, h_ws, hg_ws);
    k_gate  <<<dim3(32, 8), 256, 0, stream>>>(hg_ws, Wg2, bg2, g_ws);
    k_mlp2  <<<dim3(8, 8, 4), 512, 0, stream>>>(h_ws, W2, b2, g_ws,
                                                prev_state, prev_query, prev_key, prev_value, outp);
}

// Round 3
// 459.636 us; speedup vs baseline: 1.1334x; 1.0049x over previous
//
#include <hip/hip_runtime.h>

#define M_ 8
#define B_ 64
#define S_ 128
#define D_ 512
#define H_ 8
#define FF_ 1024
#define HD_ 64

typedef __bf16 bf16x8 __attribute__((ext_vector_type(8)));
typedef float f32x4 __attribute__((ext_vector_type(4)));

__device__ __forceinline__ float bf2f(ushort u) {
    union { unsigned int i; float f; } x; x.i = ((unsigned int)u) << 16; return x.f;
}
__device__ __forceinline__ ushort f2bf(float f) {
    union { unsigned int i; float f; } x; x.f = f;
    unsigned int i = x.i;
    return (ushort)((i + 0x7FFFu + ((i >> 16) & 1u)) >> 16);
}
__device__ __forceinline__ void pack8(const float4 a, const float4 b, uint4* dst) {
    union { ushort u[8]; uint4 v; } t;
    t.u[0] = f2bf(a.x); t.u[1] = f2bf(a.y); t.u[2] = f2bf(a.z); t.u[3] = f2bf(a.w);
    t.u[4] = f2bf(b.x); t.u[5] = f2bf(b.y); t.u[6] = f2bf(b.z); t.u[7] = f2bf(b.w);
    *dst = t.v;
}

// Barrier that does NOT drain vmcnt: LDS-visibility only. Prefetched global
// loads stay in flight across it.
__device__ __forceinline__ void lds_sync() {
    __builtin_amdgcn_sched_barrier(0);
    asm volatile("s_waitcnt lgkmcnt(0)" ::: "memory");
    __builtin_amdgcn_s_barrier();
    __builtin_amdgcn_sched_barrier(0);
}

// ---------------------------------------------------------------------------
// 512-thread split-K GEMM (64x64 output tile), BK=64 per iteration.
// Wave-group kg = tid>>8 handles K-half. Each group double-buffers its own
// LDS staging (row stride 72 shorts, bank-conflict-free for b128 frags);
// partial f32 accs combined through LDS at the end (valid in kg=0 threads).
// Xs/Ws each hold 2 groups * 2 bufs * 4608 shorts (36864 B each).
// ---------------------------------------------------------------------------
#define TSTR 72
#define TBUF 4608   // 64 * 72 shorts

__device__ __forceinline__ void gemm64_fw512(const float* __restrict__ X, int ldx,
                                             const float* __restrict__ Wc, int ldw,
                                             int K, short* Xs, short* Ws, f32x4* acc)
{
    const int tid = threadIdx.x;
    const int kg = tid >> 8, t = tid & 255;
    const int lane = t & 63, wv = t >> 6;
    const int c16 = lane & 15, koffs = (lane >> 4) * 8;
    const int xr = t >> 2, xk = (t & 3) * 16;
    const int wn = t & 63, wk = (t >> 6) * 16;
    const int K2 = K >> 1, kbase = kg * K2;
    short* Xg = Xs + kg * 2 * TBUF;
    short* Wg = Ws + kg * 2 * TBUF;
    float4 xa, xb, xc, xd; float wf[16];
    {
        const float* xp = X + xr * ldx + kbase + xk;
        xa = *(const float4*)xp;       xb = *(const float4*)(xp + 4);
        xc = *(const float4*)(xp + 8); xd = *(const float4*)(xp + 12);
        const float* wp = Wc + (kbase + wk) * ldw + wn;
        #pragma unroll
        for (int j = 0; j < 16; ++j) wf[j] = wp[j * ldw];
    }
    #pragma unroll 1
    for (int k0 = 0; k0 < K2; k0 += 64) {
        short* xs = Xg + ((k0 >> 6) & 1) * TBUF;
        short* ws = Wg + ((k0 >> 6) & 1) * TBUF;
        const int kn = kbase + ((k0 + 64 < K2) ? k0 + 64 : 0);
        const float* xp = X + xr * ldx + kn + xk;
        float4 nxa = *(const float4*)xp,       nxb = *(const float4*)(xp + 4);
        float4 nxc = *(const float4*)(xp + 8), nxd = *(const float4*)(xp + 12);
        float nwf[16];
        const float* wp = Wc + (kn + wk) * ldw + wn;
        #pragma unroll
        for (int j = 0; j < 16; ++j) nwf[j] = wp[j * ldw];
        __builtin_amdgcn_sched_barrier(0);

        pack8(xa, xb, (uint4*)&xs[xr * TSTR + xk]);
        pack8(xc, xd, (uint4*)&xs[xr * TSTR + xk + 8]);
        union { ushort u[8]; uint4 v; } tw0, tw1;
        #pragma unroll
        for (int j = 0; j < 8; ++j) { tw0.u[j] = f2bf(wf[j]); tw1.u[j] = f2bf(wf[j + 8]); }
        *(uint4*)&ws[wn * TSTR + wk]     = tw0.v;
        *(uint4*)&ws[wn * TSTR + wk + 8] = tw1.v;
        lds_sync();
        #pragma unroll
        for (int j0 = 0; j0 < 64; j0 += 32) {
            bf16x8 a = *(const bf16x8*)&xs[(16 * wv + c16) * TSTR + j0 + koffs];
            #pragma unroll
            for (int tt = 0; tt < 4; ++tt) {
                bf16x8 bfr = *(const bf16x8*)&ws[(16 * tt + c16) * TSTR + j0 + koffs];
                acc[tt] = __builtin_amdgcn_mfma_f32_16x16x32_bf16(a, bfr, acc[tt], 0, 0, 0);
            }
        }
        xa = nxa; xb = nxb; xc = nxc; xd = nxd;
        #pragma unroll
        for (int j = 0; j < 16; ++j) wf[j] = nwf[j];
    }
    __syncthreads();
    float* red = (float*)Xs;        // 16 KB needed; Xs region is 36 KB
    if (kg == 1) {
        #pragma unroll
        for (int tt = 0; tt < 4; ++tt) *(f32x4*)&red[(t * 4 + tt) * 4] = acc[tt];
    }
    __syncthreads();
    if (kg == 0) {
        #pragma unroll
        for (int tt = 0; tt < 4; ++tt) acc[tt] += *(const f32x4*)&red[(t * 4 + tt) * 4];
    }
}

__device__ __forceinline__ void gemm64_bw512(const ushort* __restrict__ X, int ldx,
                                             const float* __restrict__ Wc, int ldw,
                                             int K, short* Xs, short* Ws, f32x4* acc)
{
    const int tid = threadIdx.x;
    const int kg = tid >> 8, t = tid & 255;
    const int lane = t & 63, wv = t >> 6;
    const int c16 = lane & 15, koffs = (lane >> 4) * 8;
    const int xr = t >> 2, xk = (t & 3) * 16;
    const int wn = t & 63, wk = (t >> 6) * 16;
    const int K2 = K >> 1, kbase = kg * K2;
    short* Xg = Xs + kg * 2 * TBUF;
    short* Wg = Ws + kg * 2 * TBUF;
    uint4 xv0, xv1; float wf[16];
    {
        const ushort* xp = &X[xr * ldx + kbase + xk];
        xv0 = *(const uint4*)xp; xv1 = *(const uint4*)(xp + 8);
        const float* wp = Wc + (kbase + wk) * ldw + wn;
        #pragma unroll
        for (int j = 0; j < 16; ++j) wf[j] = wp[j * ldw];
    }
    #pragma unroll 1
    for (int k0 = 0; k0 < K2; k0 += 64) {
        short* xs = Xg + ((k0 >> 6) & 1) * TBUF;
        short* ws = Wg + ((k0 >> 6) & 1) * TBUF;
        const int kn = kbase + ((k0 + 64 < K2) ? k0 + 64 : 0);
        const ushort* xp = &X[xr * ldx + kn + xk];
        uint4 nxv0 = *(const uint4*)xp, nxv1 = *(const uint4*)(xp + 8);
        float nwf[16];
        const float* wp = Wc + (kn + wk) * ldw + wn;
        #pragma unroll
        for (int j = 0; j < 16; ++j) nwf[j] = wp[j * ldw];
        __builtin_amdgcn_sched_barrier(0);

        *(uint4*)&xs[xr * TSTR + xk]     = xv0;
        *(uint4*)&xs[xr * TSTR + xk + 8] = xv1;
        union { ushort u[8]; uint4 v; } tw0, tw1;
        #pragma unroll
        for (int j = 0; j < 8; ++j) { tw0.u[j] = f2bf(wf[j]); tw1.u[j] = f2bf(wf[j + 8]); }
        *(uint4*)&ws[wn * TSTR + wk]     = tw0.v;
        *(uint4*)&ws[wn * TSTR + wk + 8] = tw1.v;
        lds_sync();
        #pragma unroll
        for (int j0 = 0; j0 < 64; j0 += 32) {
            bf16x8 a = *(const bf16x8*)&xs[(16 * wv + c16) * TSTR + j0 + koffs];
            #pragma unroll
            for (int tt = 0; tt < 4; ++tt) {
                bf16x8 bfr = *(const bf16x8*)&ws[(16 * tt + c16) * TSTR + j0 + koffs];
                acc[tt] = __builtin_amdgcn_mfma_f32_16x16x32_bf16(a, bfr, acc[tt], 0, 0, 0);
            }
        }
        xv0 = nxv0; xv1 = nxv1;
        #pragma unroll
        for (int j = 0; j < 16; ++j) wf[j] = nwf[j];
    }
    __syncthreads();
    float* red = (float*)Xs;
    if (kg == 1) {
        #pragma unroll
        for (int tt = 0; tt < 4; ++tt) *(f32x4*)&red[(t * 4 + tt) * 4] = acc[tt];
    }
    __syncthreads();
    if (kg == 0) {
        #pragma unroll
        for (int tt = 0; tt < 4; ++tt) acc[tt] += *(const f32x4*)&red[(t * 4 + tt) * 4];
    }
}

// ---------------------------------------------------------------------------
// Kernel 1: q = prev_query @ Wq + bq. grid (D/64, M), 512 thr.
// ---------------------------------------------------------------------------
__global__ __launch_bounds__(512, 4) void k_qproj(const float* __restrict__ prev_query,
                                                  const float* __restrict__ Wq,
                                                  const float* __restrict__ bq,
                                                  ushort* __restrict__ q_ws)
{
    __shared__ __align__(16) short Xs[2 * 2 * TBUF];
    __shared__ __align__(16) short Ws[2 * 2 * TBUF];
    const int cb = blockIdx.x, m = blockIdx.y;
    f32x4 acc[4] = {};
    gemm64_fw512(prev_query + m * B_ * D_, D_, Wq + m * D_ * D_ + cb * 64, D_, D_, Xs, Ws, acc);
    const int tid = threadIdx.x;
    if (tid < 256) {
        const int lane = tid & 63, wv = tid >> 6;
        #pragma unroll
        for (int t = 0; t < 4; ++t)
            #pragma unroll
            for (int r = 0; r < 4; ++r) {
                int row = 16 * wv + (lane >> 4) * 4 + r;
                int col = cb * 64 + 16 * t + (lane & 15);
                q_ws[(m * B_ + row) * D_ + col] = f2bf(acc[t][r] + bq[m * D_ + col]);
            }
    }
}

// ---------------------------------------------------------------------------
// Kernel 2: q~[mh, b, k] = qh . Wk^T (per head). grid (8 kb, H, M), 256 thr.
// ---------------------------------------------------------------------------
__global__ __launch_bounds__(256) void k_qtilde(const ushort* __restrict__ q_ws,
                                                const float* __restrict__ Wk,
                                                ushort* __restrict__ qt_ws)
{
    const int kb = blockIdx.x, h = blockIdx.y, m = blockIdx.z;
    __shared__ __align__(16) short As[64 * 72];
    __shared__ __align__(16) short Ws[64 * 72];
    const int tid = threadIdx.x, lane = tid & 63, wv = tid >> 6;
    {   // stage A = qh [b=64][j=64]
        int r = lane, jj = wv * 16;
        const ushort* src = q_ws + (m * B_ + r) * D_ + h * HD_ + jj;
        *(uint4*)&As[r * 72 + jj]     = *(const uint4*)src;
        *(uint4*)&As[r * 72 + jj + 8] = *(const uint4*)(src + 8);
    }
    {   // stage B[j][n=k] = Wk[m][kb*64+n, h*64+j]
        int n = lane, jj = wv * 16;
        const float* src = Wk + m * D_ * D_ + (kb * 64 + n) * D_ + h * HD_ + jj;
        pack8(*(const float4*)src, *(const float4*)(src + 4), (uint4*)&Ws[n * 72 + jj]);
        pack8(*(const float4*)(src + 8), *(const float4*)(src + 12), (uint4*)&Ws[n * 72 + jj + 8]);
    }
    __syncthreads();
    const int c16 = lane & 15, koffs = (lane >> 4) * 8;
    f32x4 acc[4] = {};
    #pragma unroll
    for (int j0 = 0; j0 < 64; j0 += 32) {
        bf16x8 a = *(const bf16x8*)&As[(16 * wv + c16) * 72 + j0 + koffs];
        #pragma unroll
        for (int t = 0; t < 4; ++t) {
            bf16x8 bfr = *(const bf16x8*)&Ws[(16 * t + c16) * 72 + j0 + koffs];
            acc[t] = __builtin_amdgcn_mfma_f32_16x16x32_bf16(a, bfr, acc[t], 0, 0, 0);
        }
    }
    const int mh = m * H_ + h;
    #pragma unroll
    for (int t = 0; t < 4; ++t)
        #pragma unroll
        for (int r = 0; r < 4; ++r) {
            int row = 16 * wv + (lane >> 4) * 4 + r;     // b
            int col = kb * 64 + 16 * t + (lane & 15);    // k
            qt_ws[(mh * B_ + row) * D_ + col] = f2bf(acc[t][r]);
        }
}

// ---------------------------------------------------------------------------
// Kernel 3: per (b, half): scores -> softmax -> v~. grid (2, B), 256 thr.
// ---------------------------------------------------------------------------
__global__ __launch_bounds__(256) void k_attn2(const float* __restrict__ key_in,
                                               const float* __restrict__ value_in,
                                               const ushort* __restrict__ qt_ws,
                                               ushort* __restrict__ vt_ws)
{
    const int half = blockIdx.x, b = blockIdx.y;
    const int mh0 = half * 32;
    __shared__ __align__(16) short As[2 * 32 * 40];
    __shared__ __align__(16) short Ks[2 * 128 * 40];
    __shared__ __align__(16) short Vs[512 * 40];
    __shared__ float scs[32 * 132];
    __shared__ __align__(16) short wbuf[32 * 136];
    const int tid = threadIdx.x, lane = tid & 63, wv = tid >> 6;
    const int c16 = lane & 15, koffs = (lane >> 4) * 8;
    const int wr = wv >> 1, wc = wv & 1;
    const int BD = B_ * D_;

    // ---- phase 1: scores GEMM, out [32 mh x 128 s], K = 512 ----
    f32x4 acc[4] = {};
    const int ar = tid >> 3, ak = (tid & 7) * 4;
    const int ksr = tid >> 1, kkk = (tid & 1) * 16;
    uint2 av; float4 kv0, kv1, kv2, kv3;
    {
        av = *(const uint2*)&qt_ws[((mh0 + ar) * B_ + b) * D_ + ak];
        const float* src = key_in + ksr * BD + b * D_ + kkk;
        kv0 = *(const float4*)src;       kv1 = *(const float4*)(src + 4);
        kv2 = *(const float4*)(src + 8); kv3 = *(const float4*)(src + 12);
    }
    #pragma unroll 1
    for (int k0 = 0; k0 < D_; k0 += 32) {
        short* as_ = As + ((k0 >> 5) & 1) * (32 * 40);
        short* ks_ = Ks + ((k0 >> 5) & 1) * (128 * 40);
        const int kn = (k0 + 32 < D_) ? k0 + 32 : 0;
        uint2 nav = *(const uint2*)&qt_ws[((mh0 + ar) * B_ + b) * D_ + kn + ak];
        const float* src = key_in + ksr * BD + b * D_ + kn + kkk;
        float4 nk0 = *(const float4*)src,       nk1 = *(const float4*)(src + 4);
        float4 nk2 = *(const float4*)(src + 8), nk3 = *(const float4*)(src + 12);
        __builtin_amdgcn_sched_barrier(0);

        *(uint2*)&as_[ar * 40 + ak] = av;
        pack8(kv0, kv1, (uint4*)&ks_[ksr * 40 + kkk]);
        pack8(kv2, kv3, (uint4*)&ks_[ksr * 40 + kkk + 8]);
        lds_sync();
        bf16x8 a = *(const bf16x8*)&as_[(16 * wr + c16) * 40 + koffs];
        #pragma unroll
        for (int t = 0; t < 4; ++t) {
            bf16x8 kf = *(const bf16x8*)&ks_[(64 * wc + 16 * t + c16) * 40 + koffs];
            acc[t] = __builtin_amdgcn_mfma_f32_16x16x32_bf16(a, kf, acc[t], 0, 0, 0);
        }
        av = nav; kv0 = nk0; kv1 = nk1; kv2 = nk2; kv3 = nk3;
    }
    #pragma unroll
    for (int t = 0; t < 4; ++t)
        #pragma unroll
        for (int r = 0; r < 4; ++r) {
            int row = 16 * wr + (lane >> 4) * 4 + r;
            int col = 64 * wc + 16 * t + c16;
            scs[row * 132 + col] = acc[t][r] * 0.125f;
        }
    __syncthreads();

    // ---- softmax: 8 threads per mh-row ----
    {
        int row = tid >> 3, sub = tid & 7;
        float mx = -1e30f;
        #pragma unroll
        for (int i = 0; i < 16; ++i) mx = fmaxf(mx, scs[row * 132 + sub + 8 * i]);
        mx = fmaxf(mx, __shfl_xor(mx, 1));
        mx = fmaxf(mx, __shfl_xor(mx, 2));
        mx = fmaxf(mx, __shfl_xor(mx, 4));
        float e[16], sm = 0.f;
        #pragma unroll
        for (int i = 0; i < 16; ++i) { e[i] = __expf(scs[row * 132 + sub + 8 * i] - mx); sm += e[i]; }
        sm += __shfl_xor(sm, 1);
        sm += __shfl_xor(sm, 2);
        sm += __shfl_xor(sm, 4);
        float rinv = 1.0f / sm;
        #pragma unroll
        for (int i = 0; i < 16; ++i)
            wbuf[row * 136 + sub + 8 * i] = (short)f2bf(e[i] * rinv);
    }
    __syncthreads();

    // ---- phase 2: v~ GEMM, out [32 mh x 512 k], K = s = 128 ----
    f32x4 vacc[16] = {};
    const int hi = tid >> 6;
    #pragma unroll 1
    for (int s0 = 0; s0 < S_; s0 += 32) {
        #pragma unroll
        for (int c = 0; c < 8; ++c) {   // transposed value staging: Vs[n][ss]
            int n = lane + 64 * c;
            union { ushort u[8]; uint4 v; } tv;
            #pragma unroll
            for (int j = 0; j < 8; ++j)
                tv.u[j] = f2bf(value_in[(s0 + hi * 8 + j) * BD + b * D_ + n]);
            *(uint4*)&Vs[n * 40 + hi * 8] = tv.v;
        }
        __syncthreads();
        bf16x8 a = *(const bf16x8*)&wbuf[(16 * wr + c16) * 136 + s0 + koffs];
        #pragma unroll
        for (int t = 0; t < 16; ++t) {
            bf16x8 vf = *(const bf16x8*)&Vs[(256 * wc + 16 * t + c16) * 40 + koffs];
            vacc[t] = __builtin_amdgcn_mfma_f32_16x16x32_bf16(a, vf, vacc[t], 0, 0, 0);
        }
        __syncthreads();
    }
    #pragma unroll
    for (int t = 0; t < 16; ++t)
        #pragma unroll
        for (int r = 0; r < 4; ++r) {
            int row = 16 * wr + (lane >> 4) * 4 + r;
            int col = 256 * wc + 16 * t + c16;
            vt_ws[((mh0 + row) * B_ + b) * D_ + col] = f2bf(vacc[t][r]);
        }
}

// ---------------------------------------------------------------------------
// Kernel 4: ao = v~ . Wv + bv (per head cols). grid (H, M), 512 thr.
// ---------------------------------------------------------------------------
__global__ __launch_bounds__(512, 4) void k_aoproj(const ushort* __restrict__ vt_ws,
                                                   const float* __restrict__ Wv,
                                                   const float* __restrict__ bv,
                                                   ushort* __restrict__ ao_ws)
{
    __shared__ __align__(16) short Xs[2 * 2 * TBUF];
    __shared__ __align__(16) short Ws[2 * 2 * TBUF];
    const int h = blockIdx.x, m = blockIdx.y;
    const int mh = m * H_ + h;
    f32x4 acc[4] = {};
    gemm64_bw512(vt_ws + mh * B_ * D_, D_, Wv + m * D_ * D_ + h * HD_, D_, D_, Xs, Ws, acc);
    const int tid = threadIdx.x;
    if (tid < 256) {
        const int lane = tid & 63, wv = tid >> 6;
        #pragma unroll
        for (int t = 0; t < 4; ++t)
            #pragma unroll
            for (int r = 0; r < 4; ++r) {
                int row = 16 * wv + (lane >> 4) * 4 + r;         // b
                int col = 16 * t + (lane & 15);                  // d' in [0,64)
                ao_ws[(m * B_ + row) * D_ + h * HD_ + col] =
                    f2bf(acc[t][r] + bv[m * D_ + h * HD_ + col]);
            }
    }
}

// ---------------------------------------------------------------------------
// Kernel 5: attn_out = ao @ Wo + bo; x = relu([attn_out, prev_state]).
// grid (D/64, M), 512 thr.
// ---------------------------------------------------------------------------
__global__ __launch_bounds__(512, 4) void k_oproj(const ushort* __restrict__ ao_ws,
                                                  const float* __restrict__ Wo,
                                                  const float* __restrict__ bo,
                                                  const float* __restrict__ prev_state,
                                                  ushort* __restrict__ x_ws)
{
    __shared__ __align__(16) short Xs[2 * 2 * TBUF];
    __shared__ __align__(16) short Ws[2 * 2 * TBUF];
    const int cb = blockIdx.x, m = blockIdx.y;
    {
        int idx = threadIdx.x;                 // 512 units: 64 rows x 8 col-chunks
        int row = idx >> 3, koff = (idx & 7) * 8;
        const float* pp = prev_state + (m * B_ + row) * D_ + cb * 64 + koff;
        float4 a = *(const float4*)pp, b = *(const float4*)(pp + 4);
        a.x = fmaxf(a.x, 0.f); a.y = fmaxf(a.y, 0.f); a.z = fmaxf(a.z, 0.f); a.w = fmaxf(a.w, 0.f);
        b.x = fmaxf(b.x, 0.f); b.y = fmaxf(b.y, 0.f); b.z = fmaxf(b.z, 0.f); b.w = fmaxf(b.w, 0.f);
        pack8(a, b, (uint4*)&x_ws[(m * B_ + row) * (2 * D_) + D_ + cb * 64 + koff]);
    }
    f32x4 acc[4] = {};
    gemm64_bw512(ao_ws + m * B_ * D_, D_, Wo + m * D_ * D_ + cb * 64, D_, D_, Xs, Ws, acc);
    const int tid = threadIdx.x;
    if (tid < 256) {
        const int lane = tid & 63, wv = tid >> 6;
        #pragma unroll
        for (int t = 0; t < 4; ++t)
            #pragma unroll
            for (int r = 0; r < 4; ++r) {
                int row = 16 * wv + (lane >> 4) * 4 + r;
                int col = cb * 64 + 16 * t + (lane & 15);
                float v = fmaxf(acc[t][r] + bo[m * D_ + col], 0.0f);
                x_ws[(m * B_ + row) * (2 * D_) + col] = f2bf(v);
            }
    }
}

// ---------------------------------------------------------------------------
// Kernel 6: h = relu(x@W1+b1), hg = relu(x@Wg1+bg1). 512 thr: wave-group 0
// owns W1->h, group 1 owns Wg1->hg. X tile staged once by group 0, shared.
// BK=64 (16 iterations). grid (FF/64, M, 4 g).
// ---------------------------------------------------------------------------
__global__ __launch_bounds__(512, 4) void k_mlp1(const ushort* __restrict__ x_ws,
                                                 const float* __restrict__ W1,
                                                 const float* __restrict__ b1,
                                                 const float* __restrict__ Wg1,
                                                 const float* __restrict__ bg1,
                                                 ushort* __restrict__ h_ws,
                                                 ushort* __restrict__ hg_ws)
{
    __shared__ __align__(16) short smem[6 * TBUF];  // Xs[2 buf] | W(kg=0)[2 buf] | W(kg=1)[2 buf]
    const int cb = blockIdx.x, m = blockIdx.y, g = blockIdx.z;
    const int gm = g * M_ + m;
    const int tid = threadIdx.x;
    const int kg = tid >> 8, t = tid & 255;
    const int lane = t & 63, wv = t >> 6;
    const int c16 = lane & 15, koffs = (lane >> 4) * 8;
    const int xr = t >> 2, xk = (t & 3) * 16;
    const int wn = t & 63, wk = (t >> 6) * 16;
    const float* Wm = (kg == 0 ? W1 : Wg1) + gm * 2 * D_ * FF_ + cb * 64;
    const ushort* X = x_ws + m * B_ * 2 * D_;
    short* Xs = smem;
    short* Wg = smem + 2 * TBUF + kg * 2 * TBUF;
    f32x4 acc[4] = {};

    uint4 xv0 = {}, xv1 = {};
    float wf[16];
    {
        if (kg == 0) {
            const ushort* xp = &X[xr * (2 * D_) + xk];
            xv0 = *(const uint4*)xp; xv1 = *(const uint4*)(xp + 8);
        }
        const float* wp = Wm + wk * FF_ + wn;
        #pragma unroll
        for (int j = 0; j < 16; ++j) wf[j] = wp[j * FF_];
    }
    #pragma unroll 1
    for (int k0 = 0; k0 < 2 * D_; k0 += 64) {
        short* xs = Xs + ((k0 >> 6) & 1) * TBUF;
        short* ws = Wg + ((k0 >> 6) & 1) * TBUF;
        const int kn = (k0 + 64 < 2 * D_) ? k0 + 64 : 0;
        uint4 nxv0 = {}, nxv1 = {};
        if (kg == 0) {
            const ushort* xp = &X[xr * (2 * D_) + kn + xk];
            nxv0 = *(const uint4*)xp; nxv1 = *(const uint4*)(xp + 8);
        }
        float nwf[16];
        const float* wp = Wm + (kn + wk) * FF_ + wn;
        #pragma unroll
        for (int j = 0; j < 16; ++j) nwf[j] = wp[j * FF_];
        __builtin_amdgcn_sched_barrier(0);

        if (kg == 0) {
            *(uint4*)&xs[xr * TSTR + xk]     = xv0;
            *(uint4*)&xs[xr * TSTR + xk + 8] = xv1;
        }
        union { ushort u[8]; uint4 v; } tw0, tw1;
        #pragma unroll
        for (int j = 0; j < 8; ++j) { tw0.u[j] = f2bf(wf[j]); tw1.u[j] = f2bf(wf[j + 8]); }
        *(uint4*)&ws[wn * TSTR + wk]     = tw0.v;
        *(uint4*)&ws[wn * TSTR + wk + 8] = tw1.v;
        lds_sync();
        #pragma unroll
        for (int j0 = 0; j0 < 64; j0 += 32) {
            bf16x8 a = *(const bf16x8*)&xs[(16 * wv + c16) * TSTR + j0 + koffs];
            #pragma unroll
            for (int tt = 0; tt < 4; ++tt) {
                bf16x8 bfr = *(const bf16x8*)&ws[(16 * tt + c16) * TSTR + j0 + koffs];
                acc[tt] = __builtin_amdgcn_mfma_f32_16x16x32_bf16(a, bfr, acc[tt], 0, 0, 0);
            }
        }
        xv0 = nxv0; xv1 = nxv1;
        #pragma unroll
        for (int j = 0; j < 16; ++j) wf[j] = nwf[j];
    }
    const float* bias = (kg == 0) ? b1 : bg1;
    ushort* dst = (kg == 0) ? h_ws : hg_ws;
    #pragma unroll
    for (int tt = 0; tt < 4; ++tt)
        #pragma unroll
        for (int r = 0; r < 4; ++r) {
            int row = 16 * wv + (lane >> 4) * 4 + r;
            int col = cb * 64 + 16 * tt + c16;
            float v = fmaxf(acc[tt][r] + bias[gm * FF_ + col], 0.0f);
            dst[(gm * B_ + row) * FF_ + col] = f2bf(v);
        }
}

// ---------------------------------------------------------------------------
// Kernel 7: g = sigmoid(hg . Wg2 + bg2). grid (32 gm, 8 bblk), 256 thr.
// ---------------------------------------------------------------------------
__global__ __launch_bounds__(256) void k_gate(const ushort* __restrict__ hg_ws,
                                              const float* __restrict__ Wg2,
                                              const float* __restrict__ bg2,
                                              float* __restrict__ g_ws)
{
    const int gm = blockIdx.x, bb = blockIdx.y;
    const int tid = threadIdx.x, b = bb * 8 + (tid >> 5), q = tid & 31;
    const ushort* hp = hg_ws + (gm * B_ + b) * FF_ + q * 32;
    const float* wp = Wg2 + gm * FF_ + q * 32;
    float s = 0.f;
    #pragma unroll
    for (int j = 0; j < 32; j += 8) {
        union { ushort u[8]; uint4 v; } a;
        a.v = *(const uint4*)&hp[j];
        float4 w0 = *(const float4*)&wp[j], w1 = *(const float4*)&wp[j + 4];
        s += bf2f(a.u[0]) * w0.x + bf2f(a.u[1]) * w0.y + bf2f(a.u[2]) * w0.z + bf2f(a.u[3]) * w0.w
           + bf2f(a.u[4]) * w1.x + bf2f(a.u[5]) * w1.y + bf2f(a.u[6]) * w1.z + bf2f(a.u[7]) * w1.w;
    }
    s += __shfl_xor(s, 1);
    s += __shfl_xor(s, 2);
    s += __shfl_xor(s, 4);
    s += __shfl_xor(s, 8);
    s += __shfl_xor(s, 16);
    if (q == 0)
        g_ws[gm * B_ + b] = 1.0f / (1.0f + __expf(-(s + bg2[gm])));
}

// ---------------------------------------------------------------------------
// Kernel 8: out = tanh(relu(h@W2+b2)); new = g*out + (1-g)*prev. 512 thr.
// grid (D/64, M, 4 g). Output slot: g -> (g+1)&3.
// ---------------------------------------------------------------------------
__global__ __launch_bounds__(512, 4) void k_mlp2(const ushort* __restrict__ h_ws,
                                                 const float* __restrict__ W2,
                                                 const float* __restrict__ b2,
                                                 const float* __restrict__ g_ws,
                                                 const float* __restrict__ prev_state,
                                                 const float* __restrict__ prev_query,
                                                 const float* __restrict__ prev_key,
                                                 const float* __restrict__ prev_value,
                                                 float* __restrict__ outp)
{
    __shared__ __align__(16) short Xs[2 * 2 * TBUF];
    __shared__ __align__(16) short Ws[2 * 2 * TBUF];
    const int cb = blockIdx.x, m = blockIdx.y, g = blockIdx.z;
    const int gm = g * M_ + m;
    f32x4 acc[4] = {};
    gemm64_bw512(h_ws + gm * B_ * FF_, FF_, W2 + gm * FF_ * D_ + cb * 64, D_, FF_, Xs, Ws, acc);
    const float* prev = (g == 0) ? prev_query : (g == 1) ? prev_key
                      : (g == 2) ? prev_value : prev_state;
    const int slot = (g + 1) & 3;
    const int tid = threadIdx.x;
    if (tid < 256) {
        const int lane = tid & 63, wv = tid >> 6;
        #pragma unroll
        for (int t = 0; t < 4; ++t)
            #pragma unroll
            for (int r = 0; r < 4; ++r) {
                int row = 16 * wv + (lane >> 4) * 4 + r;
                int col = cb * 64 + 16 * t + (lane & 15);
                float v = tanhf(fmaxf(acc[t][r] + b2[gm * D_ + col], 0.0f));
                float gg = g_ws[gm * B_ + row];
                float pv = prev[(m * B_ + row) * D_ + col];
                outp[((slot * M_ + m) * B_ + row) * D_ + col] = gg * v + (1.0f - gg) * pv;
            }
    }
}

// ---------------------------------------------------------------------------
extern "C" void kernel_launch(void* const* d_in, const int* in_sizes, int n_in,
                              void* d_out, int out_size, void* d_ws, size_t ws_size,
                              hipStream_t stream)
{
    (void)in_sizes; (void)n_in; (void)out_size; (void)ws_size;
    const float* prev_state = (const float*)d_in[0];
    const float* prev_query = (const float*)d_in[1];
    const float* prev_key   = (const float*)d_in[2];
    const float* prev_value = (const float*)d_in[3];
    const float* key_in     = (const float*)d_in[4];
    const float* value_in   = (const float*)d_in[5];
    const float* Wq  = (const float*)d_in[6];
    const float* bq  = (const float*)d_in[7];
    const float* Wk  = (const float*)d_in[8];
    const float* Wv  = (const float*)d_in[10];
    const float* bv  = (const float*)d_in[11];
    const float* Wo  = (const float*)d_in[12];
    const float* bo  = (const float*)d_in[13];
    const float* W1  = (const float*)d_in[14];
    const float* b1  = (const float*)d_in[15];
    const float* W2  = (const float*)d_in[16];
    const float* b2  = (const float*)d_in[17];
    const float* Wg1 = (const float*)d_in[18];
    const float* bg1 = (const float*)d_in[19];
    const float* Wg2 = (const float*)d_in[20];
    const float* bg2 = (const float*)d_in[21];
    float* outp = (float*)d_out;

    char* ws = (char*)d_ws;
    ushort* q_ws  = (ushort*)(ws);                        // 512 KB
    ushort* ao_ws = (ushort*)(ws + (512u << 10));         // 512 KB
    ushort* x_ws  = (ushort*)(ws + (1024u << 10));        // 1 MB
    ushort* qt_ws = (ushort*)(ws + (2048u << 10));        // 4 MB (later reused as h_ws)
    ushort* vt_ws = (ushort*)(ws + (6144u << 10));        // 4 MB (later reused as hg_ws)
    ushort* h_ws  = qt_ws;                                // overlay: qt dead after k_attn2
    ushort* hg_ws = vt_ws;                                // overlay: vt dead after k_aoproj
    float*  g_ws  = (float*) (ws + (10240u << 10));       // 8 KB

    k_qproj <<<dim3(8, 8), 512, 0, stream>>>(prev_query, Wq, bq, q_ws);
    k_qtilde<<<dim3(8, 8, 8), 256, 0, stream>>>(q_ws, Wk, qt_ws);
    k_attn2 <<<dim3(2, 64), 256, 0, stream>>>(key_in, value_in, qt_ws, vt_ws);
    k_aoproj<<<dim3(8, 8), 512, 0, stream>>>(vt_ws, Wv, bv, ao_ws);
    k_oproj <<<dim3(8, 8), 512, 0, stream>>>(ao_ws, Wo, bo, prev_state, x_ws);
    k_mlp1  <<<dim3(16, 8, 4), 512, 0, stream>>>(x_ws, W1, b1, Wg1, bg1, h_ws, hg_ws);
    k_gate  <<<dim3(32, 8), 256, 0, stream>>>(hg_ws, Wg2, bg2, g_ws);
    k_mlp2  <<<dim3(8, 8, 4), 512, 0, stream>>>(h_ws, W2, b2, g_ws,
                                                prev_state, prev_query, prev_key, prev_value, outp);
}